// Round 9
// baseline (5400.752 us; speedup 1.0000x reference)
//
#include <hip/hip_runtime.h>
#include <hip/hip_bf16.h>

#define NN 100000
#define NE 800000
#define NG 2048
#define DIN 74
#define KPAD 96
#define DH 256
#define DM1 1024
#define DM2 512

typedef __attribute__((ext_vector_type(8))) short short8;
typedef __attribute__((ext_vector_type(4))) float f32x4;

__device__ inline ushort f2bf(float f) {
  unsigned u = __float_as_uint(f);
  return (ushort)((u + 0x7fffu + ((u >> 16) & 1u)) >> 16);
}
__device__ inline float bf2f(ushort h) { return __uint_as_float(((unsigned)h) << 16); }

// async 16B/lane global->LDS: lds dest is wave-uniform base + lane*16
__device__ inline void gll16(const ushort* g, ushort* l) {
  __builtin_amdgcn_global_load_lds((const __attribute__((address_space(1))) void*)g,
                                   (__attribute__((address_space(3))) void*)l, 16, 0, 0);
}

// ---------------- degrees & norms ----------------
__global__ void k_deg(const int* __restrict__ src, const int* __restrict__ dst,
                      int* __restrict__ outd, int* __restrict__ ind) {
  int e = blockIdx.x * blockDim.x + threadIdx.x;
  if (e < NE) {
    atomicAdd(&outd[src[e]], 1);
    atomicAdd(&ind[dst[e]], 1);
  }
}

__global__ void k_norm(const int* __restrict__ outd, const int* __restrict__ ind,
                       float* __restrict__ onorm, float* __restrict__ inorm) {
  int i = blockIdx.x * blockDim.x + threadIdx.x;
  if (i < NN) {
    onorm[i] = rsqrtf(fmaxf((float)outd[i], 1.f));
    inorm[i] = rsqrtf(fmaxf((float)ind[i], 1.f));
  }
}

// ---------------- CSR build (scan + counting sort) ----------------
__global__ void k_scan_block(const int* __restrict__ deg, int* __restrict__ incl,
                             int* __restrict__ bsum, int n) {
  __shared__ int s[1024];
  int t = threadIdx.x;
  int i = blockIdx.x * 1024 + t;
  int v = (i < n) ? deg[i] : 0;
  s[t] = v;
  __syncthreads();
  for (int off = 1; off < 1024; off <<= 1) {
    int x = (t >= off) ? s[t - off] : 0;
    __syncthreads();
    s[t] += x;
    __syncthreads();
  }
  if (i < n) incl[i] = s[t];
  if (t == 1023) bsum[blockIdx.x] = s[1023];
}

// single-wave exclusive scan of block sums (nb <= 128)
__global__ void k_scan_sums(int* bsum, int nb) {
  int lane = threadIdx.x & 63;
  int i0 = 2 * lane, i1 = 2 * lane + 1;
  int v0 = (i0 < nb) ? bsum[i0] : 0;
  int v1 = (i1 < nb) ? bsum[i1] : 0;
  int s = v0 + v1;
  for (int off = 1; off < 64; off <<= 1) {
    int t = __shfl_up(s, off);
    if (lane >= off) s += t;
  }
  int excl = s - (v0 + v1);
  if (i0 < nb) bsum[i0] = excl;
  if (i1 < nb) bsum[i1] = excl + v0;
}

__global__ void k_scan_add(const int* __restrict__ incl, const int* __restrict__ bsum,
                           const int* __restrict__ deg,
                           int* __restrict__ offs, int* __restrict__ cursor, int n) {
  int i = blockIdx.x * blockDim.x + threadIdx.x;
  if (i < n) {
    int v = incl[i] + bsum[i >> 10];
    offs[i + 1] = v;
    cursor[i] = v - deg[i];
    if (i == 0) offs[0] = 0;
  }
}

__global__ void k_scatter(const int* __restrict__ src, const int* __restrict__ dst,
                          int* __restrict__ cursor, int* __restrict__ ssrc) {
  int e = blockIdx.x * blockDim.x + threadIdx.x;
  if (e < NE) {
    int pos = atomicAdd(&cursor[dst[e]], 1);
    ssrc[pos] = src[e];
  }
}

// ---------------- weight convert: fp32 [k][n] -> bf16 hi/lo planes [n][k] ----------------
__global__ void k_convw(const float* __restrict__ W_in, const float* __restrict__ W_gcr,
                        const float* __restrict__ W1, const float* __restrict__ W2,
                        ushort* __restrict__ Wt0h, ushort* __restrict__ Wt0l,
                        ushort* __restrict__ Wtgh, ushort* __restrict__ Wtgl,
                        ushort* __restrict__ Wt1h, ushort* __restrict__ Wt1l,
                        ushort* __restrict__ Wt2h, ushort* __restrict__ Wt2l) {
  int idx = blockIdx.x * blockDim.x + threadIdx.x;
  const int n0 = 256 * KPAD;
  const int n1 = n0 + 10 * 65536;
  const int n2 = n1 + DM1 * DH;
  const int n3 = n2 + DM2 * DM1;
  float v;
  ushort *dh, *dl;
  int o;
  if (idx < n0) {
    int n = idx / KPAD, k = idx - n * KPAD;
    v = (k < DIN) ? W_in[k * DH + n] : 0.f;
    dh = Wt0h; dl = Wt0l; o = idx;
  } else if (idx < n1) {
    int j = idx - n0;
    int l = j >> 16, r = j & 65535;
    int n = r >> 8, k = r & 255;
    v = W_gcr[l * 65536 + k * 256 + n];
    dh = Wtgh; dl = Wtgl; o = l * 65536 + n * 256 + k;
  } else if (idx < n2) {
    int j = idx - n1;
    int n = j >> 8, k = j & 255;
    v = W1[k * DM1 + n];
    dh = Wt1h; dl = Wt1l; o = n * 256 + k;
  } else if (idx < n3) {
    int j = idx - n2;
    int n = j >> 10, k = j & 1023;
    v = W2[k * DM2 + n];
    dh = Wt2h; dl = Wt2l; o = n * 1024 + k;
  } else {
    return;
  }
  ushort hv = f2bf(v);
  dh[o] = hv;
  dl[o] = f2bf(v - bf2f(hv));
}

// ---------------- input features: fp32 [N][74] -> bf16*onorm packed [N][48] uints ----------------
__global__ void k_conv_h(const float* __restrict__ h, const float* __restrict__ onorm,
                         uint* __restrict__ hb) {
  int idx = blockIdx.x * blockDim.x + threadIdx.x;
  if (idx >= NN * 48) return;
  int r = idx / 48, j = idx - r * 48;
  float s = onorm[r];
  int k0 = j * 2;
  float v0 = (k0 < DIN) ? h[(size_t)r * DIN + k0] * s : 0.f;
  float v1 = (k0 + 1 < DIN) ? h[(size_t)r * DIN + k0 + 1] * s : 0.f;
  hb[idx] = (uint)f2bf(v0) | ((uint)f2bf(v1) << 16);
}

// ---------------- input SpMM: gather pre-scaled bf16 h rows (48 uints) ----------------
__global__ void k_spmm74(const uint* __restrict__ hb, const int* __restrict__ offs,
                         const int* __restrict__ ssrc, const float* __restrict__ inorm,
                         ushort* __restrict__ Ahi, ushort* __restrict__ Alo) {
  int row = blockIdx.x * 4 + (threadIdx.x >> 6);
  if (row >= NN) return;
  int lane = threadIdx.x & 63;
  int beg = offs[row], n = offs[row + 1] - beg;
  bool act = lane < 48;
  const uint* xb = hb + lane;
  float a0 = 0.f, a1 = 0.f;
  uint d0 = 0, d1 = 0;
  if (n > 0 && act) d0 = xb[(size_t)ssrc[beg] * 48];
  if (n > 1 && act) d1 = xb[(size_t)ssrc[beg + 1] * 48];
  for (int e = 0; e < n; ++e) {
    uint u = d0;
    d0 = d1;
    if (e + 2 < n && act) d1 = xb[(size_t)ssrc[beg + e + 2] * 48];
    a0 += __uint_as_float(u << 16);
    a1 += __uint_as_float(u & 0xffff0000u);
  }
  float win = inorm[row];
  float v0 = a0 * win, v1 = a1 * win;
  ushort h0 = f2bf(v0), h1 = f2bf(v1);
  ushort l0 = f2bf(v0 - bf2f(h0)), l1 = f2bf(v1 - bf2f(h1));
  if (act) {
    *(uint*)&Ahi[(size_t)row * KPAD + lane * 2] = (uint)h0 | ((uint)h1 << 16);
    *(uint*)&Alo[(size_t)row * KPAD + lane * 2] = (uint)l0 | ((uint)l1 << 16);
  }
}

// ---------------- FUSED gather + bf16x3 MFMA conv layer ----------------
// Block: 256 thr / 4 waves; 64 dst rows x 256 cols. xin bf16-hi pre-scaled by onorm.
// Per K-chunk (128): each wave flat-walks its 16 rows' CSR edges (depth-4 prefetch),
// fp32 accumulate (1 uint = 2 elems/lane), hi/lo split into swizzled LDS A-tile;
// then 4 MFMA K-steps with gll16-staged B. Epilogue: bias+relu (+onorm scale), bf16 store.
// LDS 64 KB -> 2 blocks/CU: gather of one block overlaps MFMA of the other.
template <int SCALE>
__global__ __launch_bounds__(256) void k_fused(
    const ushort* __restrict__ xin, const int* __restrict__ offs,
    const int* __restrict__ ssrc, const float* __restrict__ inorm,
    const float* __restrict__ oscale,
    const ushort* __restrict__ Bh, const ushort* __restrict__ Bl,
    const float* __restrict__ bias, ushort* __restrict__ xout, int M) {
  __shared__ __align__(16) ushort Ash[4 * 64 * 32], Asl[4 * 64 * 32];
  __shared__ __align__(16) ushort Bsh[256 * 32], Bsl[256 * 32];
  const int tid = threadIdx.x, lane = tid & 63, wv = tid >> 6;
  const int wn = wv * 64;
  const int quad = lane >> 4, l15 = lane & 15;
  const int r0 = blockIdx.x * 64;

  // gather lane constants: lane covers k = lane*2, lane*2+1 within the 128-chunk
  const int gsub = lane >> 4;          // 32-k subtile
  const int gc = (lane & 15) >> 2;     // 16B chunk within subtile
  const int gpos = (lane & 3) * 2;     // ushort pos within chunk
  const int bsrow = lane >> 2, bclds = lane & 3;

  f32x4 acc[4][4] = {};

  const int rb = r0 + wv * 16;
  int rend = rb + 16;
  if (rend > M) rend = M;
  const bool wvalid = (rb < M);
  const int ebeg = wvalid ? offs[rb] : 0;
  const int eend = wvalid ? offs[rend] : 0;

  for (int kc = 0; kc < 2; ++kc) {
    __syncthreads();  // previous chunk's A reads complete
    // ---- gather phase ----
    {
      const ushort* xb = xin + kc * 128 + lane * 2;
      int row = rb;
      int rlim = wvalid ? offs[row + 1] : 0;
      float a0 = 0.f, a1 = 0.f;
      auto flushrow = [&](int r, float win) {
        int tr = wv * 16 + (r - rb);
        int addr = gsub * 2048 + tr * 32 + ((gc ^ ((tr >> 1) & 3)) << 3) + gpos;
        float v0 = a0 * win, v1 = a1 * win;
        ushort h0 = f2bf(v0), h1 = f2bf(v1);
        *(uint*)&Ash[addr] = (uint)h0 | ((uint)h1 << 16);
        ushort l0 = f2bf(v0 - bf2f(h0)), l1 = f2bf(v1 - bf2f(h1));
        *(uint*)&Asl[addr] = (uint)l0 | ((uint)l1 << 16);
      };
      uint d0 = 0, d1 = 0, d2 = 0, d3 = 0;
      int cnt = eend - ebeg;
#define GLOADF(dj, idx) dj = *(const uint*)(xb + (size_t)ssrc[idx] * DH);
      if (cnt > 0) GLOADF(d0, ebeg)
      if (cnt > 1) GLOADF(d1, ebeg + 1)
      if (cnt > 2) GLOADF(d2, ebeg + 2)
      if (cnt > 3) GLOADF(d3, ebeg + 3)
      int e = ebeg;
#define GSTEPF(dj) { \
      while (e >= rlim) { flushrow(row, inorm[row]); a0 = a1 = 0.f; ++row; rlim = offs[row + 1]; } \
      uint u = dj; if (e + 4 < eend) GLOADF(dj, e + 4) \
      a0 += __uint_as_float(u << 16); a1 += __uint_as_float(u & 0xffff0000u); ++e; }
      while (e < eend) {
        GSTEPF(d0) if (e >= eend) break;
        GSTEPF(d1) if (e >= eend) break;
        GSTEPF(d2) if (e >= eend) break;
        GSTEPF(d3)
      }
#undef GSTEPF
#undef GLOADF
      while (row < rb + 16) {  // flush current partial + remaining empty/pad rows
        float win = (row < M) ? inorm[row] : 0.f;
        flushrow(row, win);
        a0 = a1 = 0.f;
        ++row;
      }
    }
    __syncthreads();  // A-tile visible
    // ---- 4 MFMA K-steps over this 128-chunk ----
    for (int s = 0; s < 4; ++s) {
      const int k0 = kc * 128 + s * 32;
#pragma unroll
      for (int i = 0; i < 4; ++i) {
        int rowb = i * 64 + 16 * wv + bsrow;
        int cg = bclds ^ ((rowb >> 1) & 3);
        size_t go = (size_t)rowb * DH + k0 + cg * 8;
        gll16(Bh + go, &Bsh[(i * 64 + 16 * wv) * 32]);
        gll16(Bl + go, &Bsl[(i * 64 + 16 * wv) * 32]);
      }
      __syncthreads();  // B staged (vmcnt drained by compiler before barrier)
      short8 ah[4], al[4];
#pragma unroll
      for (int t = 0; t < 4; ++t) {
        int r = t * 16 + l15;
        int sa = (quad ^ ((r >> 1) & 3)) << 3;
        ah[t] = *(const short8*)&Ash[s * 2048 + r * 32 + sa];
        al[t] = *(const short8*)&Asl[s * 2048 + r * 32 + sa];
      }
#pragma unroll
      for (int nt = 0; nt < 4; ++nt) {
        int rbq = wn + nt * 16 + l15;
        int sb = (quad ^ ((rbq >> 1) & 3)) << 3;
        short8 bh = *(const short8*)&Bsh[rbq * 32 + sb];
        short8 bl = *(const short8*)&Bsl[rbq * 32 + sb];
#pragma unroll
        for (int mt = 0; mt < 4; ++mt) {
          acc[mt][nt] = __builtin_amdgcn_mfma_f32_16x16x32_bf16(ah[mt], bh, acc[mt][nt], 0, 0, 0);
          acc[mt][nt] = __builtin_amdgcn_mfma_f32_16x16x32_bf16(ah[mt], bl, acc[mt][nt], 0, 0, 0);
          acc[mt][nt] = __builtin_amdgcn_mfma_f32_16x16x32_bf16(al[mt], bh, acc[mt][nt], 0, 0, 0);
        }
      }
      __syncthreads();  // B consumed
    }
  }

  float bv[4];
#pragma unroll
  for (int nt = 0; nt < 4; ++nt) bv[nt] = bias[wn + nt * 16 + l15];
#pragma unroll
  for (int mt = 0; mt < 4; ++mt) {
#pragma unroll
    for (int r = 0; r < 4; ++r) {
      int gr = r0 + mt * 16 + quad * 4 + r;
      if (gr >= M) continue;
      float osc = SCALE ? oscale[gr] : 1.f;
#pragma unroll
      for (int nt = 0; nt < 4; ++nt) {
        float v = fmaxf(acc[mt][nt][r] + bv[nt], 0.f);
        if (SCALE) v *= osc;
        xout[(size_t)gr * DH + wn + nt * 16 + l15] = f2bf(v);
      }
    }
  }
}

// ---------------- async-staged bf16x3 MFMA GEMM (layer-0 + MLP tail) ----------------
// ACT: 0=none 1=relu 2=leaky(0.01). OUT: 0=fp32 C0, 1=bf16 hi C0, 2=planes C0/C1
// SCALE: multiply output by oscale[row] (after ACT) before store.
template <int ACT, int OUT, int SCALE>
__global__ __launch_bounds__(512, 4) void k_mfma(
    const ushort* __restrict__ Ah, const ushort* __restrict__ Al,
    const ushort* __restrict__ Bh, const ushort* __restrict__ Bl,
    const float* __restrict__ bias, const float* __restrict__ oscale,
    void* __restrict__ C0, void* __restrict__ C1,
    int M, int K, int Nc) {
  __shared__ __align__(16) ushort Ash[128 * 32], Asl[128 * 32];
  __shared__ __align__(16) ushort Bsh[256 * 32], Bsl[256 * 32];
  const int tid = threadIdx.x, lane = tid & 63, wv = tid >> 6;
  const int wm = (wv >> 2) * 64, wn = (wv & 3) * 64;
  const int quad = lane >> 4, l15 = lane & 15;
  const int r0 = blockIdx.x * 128, c0 = blockIdx.y * 256;

  const int srow = lane >> 2, clds = lane & 3;
  const int arow = 16 * wv + srow;
  const int acg = clds ^ ((arow >> 1) & 3);
  int agr = r0 + arow;
  if (agr > M - 1) agr = M - 1;
  const size_t aoff = (size_t)agr * K + acg * 8;
  const int brow0 = 16 * wv + srow, brow1 = brow0 + 128;
  const int bcg0 = clds ^ ((brow0 >> 1) & 3);
  const int bcg1 = clds ^ ((brow1 >> 1) & 3);
  const size_t boff0 = (size_t)(c0 + brow0) * K + bcg0 * 8;
  const size_t boff1 = (size_t)(c0 + brow1) * K + bcg1 * 8;
  ushort* lAh = &Ash[(16 * wv) * 32];
  ushort* lAl = &Asl[(16 * wv) * 32];
  ushort* lB0h = &Bsh[(16 * wv) * 32];
  ushort* lB0l = &Bsl[(16 * wv) * 32];
  ushort* lB1h = &Bsh[(16 * wv + 128) * 32];
  ushort* lB1l = &Bsl[(16 * wv + 128) * 32];

  f32x4 acc[4][4] = {};
  const int nk = K >> 5;
  for (int s = 0; s < nk; ++s) {
    const int k0 = s << 5;
    __syncthreads();
    gll16(Ah + aoff + k0, lAh);
    gll16(Al + aoff + k0, lAl);
    gll16(Bh + boff0 + k0, lB0h);
    gll16(Bl + boff0 + k0, lB0l);
    gll16(Bh + boff1 + k0, lB1h);
    gll16(Bl + boff1 + k0, lB1l);
    __syncthreads();
    short8 ah[4], al[4];
#pragma unroll
    for (int t = 0; t < 4; ++t) {
      int r = wm + t * 16 + l15;
      int sa = (quad ^ ((r >> 1) & 3)) << 3;
      ah[t] = *(const short8*)&Ash[r * 32 + sa];
      al[t] = *(const short8*)&Asl[r * 32 + sa];
    }
#pragma unroll
    for (int nt = 0; nt < 4; ++nt) {
      int rb = wn + nt * 16 + l15;
      int sb = (quad ^ ((rb >> 1) & 3)) << 3;
      short8 bh = *(const short8*)&Bsh[rb * 32 + sb];
      short8 bl = *(const short8*)&Bsl[rb * 32 + sb];
#pragma unroll
      for (int mt = 0; mt < 4; ++mt) {
        acc[mt][nt] = __builtin_amdgcn_mfma_f32_16x16x32_bf16(ah[mt], bh, acc[mt][nt], 0, 0, 0);
        acc[mt][nt] = __builtin_amdgcn_mfma_f32_16x16x32_bf16(ah[mt], bl, acc[mt][nt], 0, 0, 0);
        acc[mt][nt] = __builtin_amdgcn_mfma_f32_16x16x32_bf16(al[mt], bh, acc[mt][nt], 0, 0, 0);
      }
    }
  }

  float bv[4];
#pragma unroll
  for (int nt = 0; nt < 4; ++nt) bv[nt] = bias[c0 + wn + nt * 16 + l15];
#pragma unroll
  for (int mt = 0; mt < 4; ++mt) {
#pragma unroll
    for (int r = 0; r < 4; ++r) {
      int gr = r0 + wm + mt * 16 + quad * 4 + r;
      if (gr >= M) continue;
      float osc = SCALE ? oscale[gr] : 1.f;
#pragma unroll
      for (int nt = 0; nt < 4; ++nt) {
        int gc = c0 + wn + nt * 16 + l15;
        float v = acc[mt][nt][r] + bv[nt];
        if (ACT == 1) v = fmaxf(v, 0.f);
        if (ACT == 2) v = (v > 0.f) ? v : 0.01f * v;
        if (SCALE) v *= osc;
        size_t idx = (size_t)gr * Nc + gc;
        if (OUT == 0) {
          ((float*)C0)[idx] = v;
        } else if (OUT == 1) {
          ((ushort*)C0)[idx] = f2bf(v);
        } else {
          ushort hv = f2bf(v);
          ((ushort*)C0)[idx] = hv;
          ((ushort*)C1)[idx] = f2bf(v - bf2f(hv));
        }
      }
    }
  }
}

// ---------------- pooling + tail ----------------
__global__ void k_gbounds(const int* __restrict__ gid, int* __restrict__ gstart) {
  int g = blockIdx.x * blockDim.x + threadIdx.x;
  if (g > NG) return;
  int lo = 0, hi = NN;
  while (lo < hi) {
    int mid = (lo + hi) >> 1;
    if (gid[mid] < g) lo = mid + 1; else hi = mid;
  }
  gstart[g] = lo;
}

__global__ void k_pool(const ushort* __restrict__ xh, const int* __restrict__ gstart,
                       ushort* __restrict__ ph, ushort* __restrict__ pl) {
  int g = blockIdx.x * 4 + (threadIdx.x >> 6);
  if (g >= NG) return;
  int lane = threadIdx.x & 63;
  int beg = gstart[g], end = gstart[g + 1];
  float a0 = 0.f, a1 = 0.f, a2 = 0.f, a3 = 0.f;
  for (int r = beg; r < end; ++r) {
    uint2 u = *(const uint2*)(xh + (size_t)r * DH + lane * 4);
    a0 += __uint_as_float(u.x << 16);
    a1 += __uint_as_float(u.x & 0xffff0000u);
    a2 += __uint_as_float(u.y << 16);
    a3 += __uint_as_float(u.y & 0xffff0000u);
  }
  float inv = 1.f / fmaxf((float)(end - beg), 1.f);
  float o[4] = {a0 * inv, a1 * inv, a2 * inv, a3 * inv};
  ushort4 hv, lv;
  hv.x = f2bf(o[0]); lv.x = f2bf(o[0] - bf2f(hv.x));
  hv.y = f2bf(o[1]); lv.y = f2bf(o[1] - bf2f(hv.y));
  hv.z = f2bf(o[2]); lv.z = f2bf(o[2] - bf2f(hv.z));
  hv.w = f2bf(o[3]); lv.w = f2bf(o[3] - bf2f(hv.w));
  *(ushort4*)(ph + (size_t)g * DH + lane * 4) = hv;
  *(ushort4*)(pl + (size_t)g * DH + lane * 4) = lv;
}

__global__ void k_out(const float* __restrict__ z2, const float* __restrict__ W3,
                      const float* __restrict__ b3, float* __restrict__ out) {
  int g = blockIdx.x * 4 + (threadIdx.x >> 6);
  if (g >= NG) return;
  int lane = threadIdx.x & 63;
  float s = 0.f;
  const float* zr = z2 + (size_t)g * DM2;
  for (int k = lane; k < DM2; k += 64) s += zr[k] * W3[k];
  for (int off = 32; off > 0; off >>= 1) s += __shfl_down(s, off);
  if (lane == 0) out[g] = s + b3[0];
}

// ---------------- launcher ----------------
extern "C" void kernel_launch(void* const* d_in, const int* in_sizes, int n_in,
                              void* d_out, int out_size, void* d_ws, size_t ws_size,
                              hipStream_t stream) {
  (void)in_sizes; (void)n_in; (void)out_size; (void)ws_size;
  const float* h     = (const float*)d_in[0];
  const int*   src   = (const int*)d_in[1];
  const int*   dst   = (const int*)d_in[2];
  const int*   gid   = (const int*)d_in[3];
  const float* W_in  = (const float*)d_in[4];
  const float* b_in  = (const float*)d_in[5];
  const float* W_gcr = (const float*)d_in[6];
  const float* b_gcr = (const float*)d_in[7];
  const float* W1    = (const float*)d_in[8];
  const float* b1    = (const float*)d_in[9];
  const float* W2    = (const float*)d_in[10];
  const float* b2    = (const float*)d_in[11];
  const float* W3    = (const float*)d_in[12];
  const float* b3    = (const float*)d_in[13];
  float* out = (float*)d_out;

  char* p = (char*)d_ws;
  auto alloc = [&](size_t bytes) {
    char* q = p;
    p += (bytes + 255) & ~(size_t)255;
    return q;
  };
  int*    outdeg = (int*)alloc((size_t)NN * 4);
  int*    indeg  = (int*)alloc((size_t)NN * 4);
  float*  onorm  = (float*)alloc((size_t)NN * 4);
  float*  inorm  = (float*)alloc((size_t)NN * 4);
  int*    incl   = (int*)alloc((size_t)NN * 4);
  int*    bsum   = (int*)alloc(128 * 4);
  int*    offs   = (int*)alloc((size_t)(NN + 1) * 4);
  int*    cursor = (int*)alloc((size_t)NN * 4);
  int*    ssrc   = (int*)alloc((size_t)NE * 4);
  int*    gstart = (int*)alloc((size_t)(NG + 1) * 4);
  uint*   hb     = (uint*)alloc((size_t)NN * 48 * 4);
  ushort* xh0    = (ushort*)alloc((size_t)NN * DH * 2);
  ushort* xh1    = (ushort*)alloc((size_t)NN * DH * 2);
  ushort* Ahi    = (ushort*)alloc((size_t)NN * KPAD * 2);
  ushort* Alo    = (ushort*)alloc((size_t)NN * KPAD * 2);
  ushort* Wt0h   = (ushort*)alloc((size_t)256 * KPAD * 2);
  ushort* Wt0l   = (ushort*)alloc((size_t)256 * KPAD * 2);
  ushort* Wtgh   = (ushort*)alloc((size_t)10 * 65536 * 2);
  ushort* Wtgl   = (ushort*)alloc((size_t)10 * 65536 * 2);
  ushort* Wt1h   = (ushort*)alloc((size_t)DM1 * DH * 2);
  ushort* Wt1l   = (ushort*)alloc((size_t)DM1 * DH * 2);
  ushort* Wt2h   = (ushort*)alloc((size_t)DM2 * DM1 * 2);
  ushort* Wt2l   = (ushort*)alloc((size_t)DM2 * DM1 * 2);
  ushort* plh    = (ushort*)alloc((size_t)NG * DH * 2);
  ushort* pll    = (ushort*)alloc((size_t)NG * DH * 2);
  ushort* z1h    = (ushort*)alloc((size_t)NG * DM1 * 2);
  ushort* z1l    = (ushort*)alloc((size_t)NG * DM1 * 2);
  float*  z2     = (float*)alloc((size_t)NG * DM2 * 4);

  hipMemsetAsync(outdeg, 0, (size_t)NN * 4, stream);
  hipMemsetAsync(indeg, 0, (size_t)NN * 4, stream);
  k_deg<<<(NE + 255) / 256, 256, 0, stream>>>(src, dst, outdeg, indeg);
  k_norm<<<(NN + 255) / 256, 256, 0, stream>>>(outdeg, indeg, onorm, inorm);
  int nb = (NN + 1023) / 1024;
  k_scan_block<<<nb, 1024, 0, stream>>>(indeg, incl, bsum, NN);
  k_scan_sums<<<1, 64, 0, stream>>>(bsum, nb);
  k_scan_add<<<(NN + 255) / 256, 256, 0, stream>>>(incl, bsum, indeg, offs, cursor, NN);
  k_scatter<<<(NE + 255) / 256, 256, 0, stream>>>(src, dst, cursor, ssrc);

  const int nconv = 256 * KPAD + 10 * 65536 + DM1 * DH + DM2 * DM1;
  k_convw<<<(nconv + 255) / 256, 256, 0, stream>>>(W_in, W_gcr, W1, W2,
                                                   Wt0h, Wt0l, Wtgh, Wtgl,
                                                   Wt1h, Wt1l, Wt2h, Wt2l);
  k_conv_h<<<(NN * 48 + 255) / 256, 256, 0, stream>>>(h, onorm, hb);

  // input conv: gather pre-scaled bf16 h (pad 96), GEMM 96->256, no act,
  // output bf16-hi scaled by onorm (ready for next gather)
  k_spmm74<<<(NN + 3) / 4, 256, 0, stream>>>(hb, offs, ssrc, inorm, Ahi, Alo);
  dim3 gmm((NN + 127) / 128, 1);
  k_mfma<0, 1, 1><<<gmm, 512, 0, stream>>>(Ahi, Alo, Wt0h, Wt0l, b_in, onorm,
                                           xh0, nullptr, NN, KPAD, DH);

  // 10 fused conv layers (gather+GEMM+relu); layers 0..8 output pre-scaled by onorm
  ushort* xin = xh0;
  ushort* xout = xh1;
  for (int li = 0; li < 10; ++li) {
    const ushort* bh = Wtgh + (size_t)li * 65536;
    const ushort* bl = Wtgl + (size_t)li * 65536;
    const float* bb = b_gcr + li * 256;
    if (li < 9)
      k_fused<1><<<(NN + 63) / 64, 256, 0, stream>>>(xin, offs, ssrc, inorm, onorm,
                                                     bh, bl, bb, xout, NN);
    else
      k_fused<0><<<(NN + 63) / 64, 256, 0, stream>>>(xin, offs, ssrc, inorm, onorm,
                                                     bh, bl, bb, xout, NN);
    ushort* t = xin; xin = xout; xout = t;
  }
  // after 10 layers result is in xin (= xh0), unscaled

  k_gbounds<<<(NG + 1 + 255) / 256, 256, 0, stream>>>(gid, gstart);
  k_pool<<<(NG + 3) / 4, 256, 0, stream>>>(xin, gstart, plh, pll);

  dim3 gt1(NG / 128, DM1 / 256);
  k_mfma<2, 2, 0><<<gt1, 512, 0, stream>>>(plh, pll, Wt1h, Wt1l, b1, nullptr,
                                           z1h, z1l, NG, DH, DM1);
  dim3 gt2(NG / 128, DM2 / 256);
  k_mfma<2, 0, 0><<<gt2, 512, 0, stream>>>(z1h, z1l, Wt2h, Wt2l, b2, nullptr,
                                           z2, nullptr, NG, DM1, DM2);
  k_out<<<(NG + 3) / 4, 256, 0, stream>>>(z2, W3, b3, out);
}

// Round 10
// 1697.579 us; speedup vs baseline: 3.1814x; 3.1814x over previous
//
#include <hip/hip_runtime.h>
#include <hip/hip_bf16.h>

#define NN 100000
#define NE 800000
#define NG 2048
#define DIN 74
#define KPAD 96
#define DH 256
#define DM1 1024
#define DM2 512

typedef __attribute__((ext_vector_type(8))) short short8;
typedef __attribute__((ext_vector_type(4))) float f32x4;

__device__ inline ushort f2bf(float f) {
  unsigned u = __float_as_uint(f);
  return (ushort)((u + 0x7fffu + ((u >> 16) & 1u)) >> 16);
}
__device__ inline float bf2f(ushort h) { return __uint_as_float(((unsigned)h) << 16); }

// async 16B/lane global->LDS: lds dest is wave-uniform base + lane*16
__device__ inline void gll16(const ushort* g, ushort* l) {
  __builtin_amdgcn_global_load_lds((const __attribute__((address_space(1))) void*)g,
                                   (__attribute__((address_space(3))) void*)l, 16, 0, 0);
}

// ---------------- degrees & norms ----------------
__global__ void k_deg(const int* __restrict__ src, const int* __restrict__ dst,
                      int* __restrict__ outd, int* __restrict__ ind) {
  int e = blockIdx.x * blockDim.x + threadIdx.x;
  if (e < NE) {
    atomicAdd(&outd[src[e]], 1);
    atomicAdd(&ind[dst[e]], 1);
  }
}

__global__ void k_norm(const int* __restrict__ outd, const int* __restrict__ ind,
                       float* __restrict__ onorm, float* __restrict__ inorm) {
  int i = blockIdx.x * blockDim.x + threadIdx.x;
  if (i < NN) {
    onorm[i] = rsqrtf(fmaxf((float)outd[i], 1.f));
    inorm[i] = rsqrtf(fmaxf((float)ind[i], 1.f));
  }
}

// ---------------- CSR build (scan + counting sort) ----------------
__global__ void k_scan_block(const int* __restrict__ deg, int* __restrict__ incl,
                             int* __restrict__ bsum, int n) {
  __shared__ int s[1024];
  int t = threadIdx.x;
  int i = blockIdx.x * 1024 + t;
  int v = (i < n) ? deg[i] : 0;
  s[t] = v;
  __syncthreads();
  for (int off = 1; off < 1024; off <<= 1) {
    int x = (t >= off) ? s[t - off] : 0;
    __syncthreads();
    s[t] += x;
    __syncthreads();
  }
  if (i < n) incl[i] = s[t];
  if (t == 1023) bsum[blockIdx.x] = s[1023];
}

// single-wave exclusive scan of block sums (nb <= 128)
__global__ void k_scan_sums(int* bsum, int nb) {
  int lane = threadIdx.x & 63;
  int i0 = 2 * lane, i1 = 2 * lane + 1;
  int v0 = (i0 < nb) ? bsum[i0] : 0;
  int v1 = (i1 < nb) ? bsum[i1] : 0;
  int s = v0 + v1;
  for (int off = 1; off < 64; off <<= 1) {
    int t = __shfl_up(s, off);
    if (lane >= off) s += t;
  }
  int excl = s - (v0 + v1);
  if (i0 < nb) bsum[i0] = excl;
  if (i1 < nb) bsum[i1] = excl + v0;
}

__global__ void k_scan_add(const int* __restrict__ incl, const int* __restrict__ bsum,
                           const int* __restrict__ deg,
                           int* __restrict__ offs, int* __restrict__ cursor, int n) {
  int i = blockIdx.x * blockDim.x + threadIdx.x;
  if (i < n) {
    int v = incl[i] + bsum[i >> 10];
    offs[i + 1] = v;
    cursor[i] = v - deg[i];
    if (i == 0) offs[0] = 0;
  }
}

__global__ void k_scatter(const int* __restrict__ src, const int* __restrict__ dst,
                          int* __restrict__ cursor, int* __restrict__ ssrc) {
  int e = blockIdx.x * blockDim.x + threadIdx.x;
  if (e < NE) {
    int pos = atomicAdd(&cursor[dst[e]], 1);
    ssrc[pos] = src[e];
  }
}

// ---------------- weight convert: fp32 [k][n] -> bf16 hi/lo planes [n][k] ----------------
__global__ void k_convw(const float* __restrict__ W_in, const float* __restrict__ W_gcr,
                        const float* __restrict__ W1, const float* __restrict__ W2,
                        ushort* __restrict__ Wt0h, ushort* __restrict__ Wt0l,
                        ushort* __restrict__ Wtgh, ushort* __restrict__ Wtgl,
                        ushort* __restrict__ Wt1h, ushort* __restrict__ Wt1l,
                        ushort* __restrict__ Wt2h, ushort* __restrict__ Wt2l) {
  int idx = blockIdx.x * blockDim.x + threadIdx.x;
  const int n0 = 256 * KPAD;
  const int n1 = n0 + 10 * 65536;
  const int n2 = n1 + DM1 * DH;
  const int n3 = n2 + DM2 * DM1;
  float v;
  ushort *dh, *dl;
  int o;
  if (idx < n0) {
    int n = idx / KPAD, k = idx - n * KPAD;
    v = (k < DIN) ? W_in[k * DH + n] : 0.f;
    dh = Wt0h; dl = Wt0l; o = idx;
  } else if (idx < n1) {
    int j = idx - n0;
    int l = j >> 16, r = j & 65535;
    int n = r >> 8, k = r & 255;
    v = W_gcr[l * 65536 + k * 256 + n];
    dh = Wtgh; dl = Wtgl; o = l * 65536 + n * 256 + k;
  } else if (idx < n2) {
    int j = idx - n1;
    int n = j >> 8, k = j & 255;
    v = W1[k * DM1 + n];
    dh = Wt1h; dl = Wt1l; o = n * 256 + k;
  } else if (idx < n3) {
    int j = idx - n2;
    int n = j >> 10, k = j & 1023;
    v = W2[k * DM2 + n];
    dh = Wt2h; dl = Wt2l; o = n * 1024 + k;
  } else {
    return;
  }
  ushort hv = f2bf(v);
  dh[o] = hv;
  dl[o] = f2bf(v - bf2f(hv));
}

// ---------------- input features: fp32 [N][74] -> bf16*onorm packed [N][48] uints ----------------
__global__ void k_conv_h(const float* __restrict__ h, const float* __restrict__ onorm,
                         uint* __restrict__ hb) {
  int idx = blockIdx.x * blockDim.x + threadIdx.x;
  if (idx >= NN * 48) return;
  int r = idx / 48, j = idx - r * 48;
  float s = onorm[r];
  int k0 = j * 2;
  float v0 = (k0 < DIN) ? h[(size_t)r * DIN + k0] * s : 0.f;
  float v1 = (k0 + 1 < DIN) ? h[(size_t)r * DIN + k0 + 1] * s : 0.f;
  hb[idx] = (uint)f2bf(v0) | ((uint)f2bf(v1) << 16);
}

// ---------------- input SpMM: gather pre-scaled bf16 h rows (48 uints) ----------------
__global__ void k_spmm74(const uint* __restrict__ hb, const int* __restrict__ offs,
                         const int* __restrict__ ssrc, const float* __restrict__ inorm,
                         ushort* __restrict__ Ahi, ushort* __restrict__ Alo) {
  int row = blockIdx.x * 4 + (threadIdx.x >> 6);
  if (row >= NN) return;
  int lane = threadIdx.x & 63;
  int beg = offs[row], n = offs[row + 1] - beg;
  bool act = lane < 48;
  const uint* xb = hb + lane;
  float a0 = 0.f, a1 = 0.f;
  uint d0 = 0, d1 = 0;
  if (n > 0 && act) d0 = xb[(size_t)ssrc[beg] * 48];
  if (n > 1 && act) d1 = xb[(size_t)ssrc[beg + 1] * 48];
  for (int e = 0; e < n; ++e) {
    uint u = d0;
    d0 = d1;
    if (e + 2 < n && act) d1 = xb[(size_t)ssrc[beg + e + 2] * 48];
    a0 += __uint_as_float(u << 16);
    a1 += __uint_as_float(u & 0xffff0000u);
  }
  float win = inorm[row];
  float v0 = a0 * win, v1 = a1 * win;
  ushort h0 = f2bf(v0), h1 = f2bf(v1);
  ushort l0 = f2bf(v0 - bf2f(h0)), l1 = f2bf(v1 - bf2f(h1));
  if (act) {
    *(uint*)&Ahi[(size_t)row * KPAD + lane * 2] = (uint)h0 | ((uint)h1 << 16);
    *(uint*)&Alo[(size_t)row * KPAD + lane * 2] = (uint)l0 | ((uint)l1 << 16);
  }
}

// ---------------- conv SpMM: gather bf16-hi pre-scaled x, write single bf16-hi A plane ----------------
// depth-4 edge pipeline, uint2 (8B = 4 bf16) per lane per edge.
__global__ void k_spmm1(const ushort* __restrict__ xin, const int* __restrict__ offs,
                        const int* __restrict__ ssrc, const float* __restrict__ inorm,
                        ushort* __restrict__ Ah) {
  int row = blockIdx.x * 4 + (threadIdx.x >> 6);
  if (row >= NN) return;
  int lane = threadIdx.x & 63;
  int beg = offs[row], n = offs[row + 1] - beg;
  float a0 = 0.f, a1 = 0.f, a2 = 0.f, a3 = 0.f;
  uint2 z = {0, 0};
  uint2 u0 = z, u1 = z, u2 = z, u3 = z;
#define LOADJ(uj, idx) { int s_ = ssrc[idx]; \
    uj = *(const uint2*)(xin + (size_t)s_ * DH + lane * 4); }
  if (n > 0) LOADJ(u0, beg)
  if (n > 1) LOADJ(u1, beg + 1)
  if (n > 2) LOADJ(u2, beg + 2)
  if (n > 3) LOADJ(u3, beg + 3)
  int e = 0;
#define STEP(uj) { uint2 fu = uj; \
    if (e + 4 < n) LOADJ(uj, beg + e + 4) \
    a0 += __uint_as_float(fu.x << 16); \
    a1 += __uint_as_float(fu.x & 0xffff0000u); \
    a2 += __uint_as_float(fu.y << 16); \
    a3 += __uint_as_float(fu.y & 0xffff0000u); ++e; }
  while (e < n) {
    STEP(u0) if (e >= n) break;
    STEP(u1) if (e >= n) break;
    STEP(u2) if (e >= n) break;
    STEP(u3)
  }
#undef STEP
#undef LOADJ
  float win = inorm[row];
  ushort4 hv;
  hv.x = f2bf(a0 * win);
  hv.y = f2bf(a1 * win);
  hv.z = f2bf(a2 * win);
  hv.w = f2bf(a3 * win);
  *(ushort4*)(Ah + (size_t)row * DH + lane * 4) = hv;
}

// ---------------- async-staged bf16 MFMA GEMM ----------------
// A: bf16-hi plane [M][K] (+ optional lo plane when ALO=1); B: hi/lo planes [N][K].
// Staging via global_load_lds (16B/lane). XOR chunk swizzle -> free 2-way frag reads.
// ACT: 0=none 1=relu 2=leaky(0.01). OUT: 0=fp32 C0, 1=bf16 hi C0, 2=planes C0/C1
// SCALE: multiply output by oscale[row] (after ACT). ALO: A lo-plane present (3 vs 2 MFMA).
template <int ACT, int OUT, int SCALE, int ALO>
__global__ __launch_bounds__(512, 4) void k_mfma(
    const ushort* __restrict__ Ah, const ushort* __restrict__ Al,
    const ushort* __restrict__ Bh, const ushort* __restrict__ Bl,
    const float* __restrict__ bias, const float* __restrict__ oscale,
    void* __restrict__ C0, void* __restrict__ C1,
    int M, int K, int Nc) {
  __shared__ __align__(16) ushort Ash[128 * 32];
  __shared__ __align__(16) ushort Asl[ALO ? 128 * 32 : 8];
  __shared__ __align__(16) ushort Bsh[256 * 32], Bsl[256 * 32];
  const int tid = threadIdx.x, lane = tid & 63, wv = tid >> 6;
  const int wm = (wv >> 2) * 64, wn = (wv & 3) * 64;
  const int quad = lane >> 4, l15 = lane & 15;
  const int r0 = blockIdx.x * 128, c0 = blockIdx.y * 256;

  const int srow = lane >> 2, clds = lane & 3;
  const int arow = 16 * wv + srow;
  const int acg = clds ^ ((arow >> 1) & 3);
  int agr = r0 + arow;
  if (agr > M - 1) agr = M - 1;  // clamp; epilogue masks stores
  const size_t aoff = (size_t)agr * K + acg * 8;
  const int brow0 = 16 * wv + srow, brow1 = brow0 + 128;
  const int bcg0 = clds ^ ((brow0 >> 1) & 3);
  const int bcg1 = clds ^ ((brow1 >> 1) & 3);
  const size_t boff0 = (size_t)(c0 + brow0) * K + bcg0 * 8;
  const size_t boff1 = (size_t)(c0 + brow1) * K + bcg1 * 8;
  ushort* lAh = &Ash[(16 * wv) * 32];
  ushort* lAl = &Asl[ALO ? (16 * wv) * 32 : 0];
  ushort* lB0h = &Bsh[(16 * wv) * 32];
  ushort* lB0l = &Bsl[(16 * wv) * 32];
  ushort* lB1h = &Bsh[(16 * wv + 128) * 32];
  ushort* lB1l = &Bsl[(16 * wv + 128) * 32];

  f32x4 acc[4][4] = {};
  const int nk = K >> 5;
  for (int s = 0; s < nk; ++s) {
    const int k0 = s << 5;
    __syncthreads();
    gll16(Ah + aoff + k0, lAh);
    if (ALO) gll16(Al + aoff + k0, lAl);
    gll16(Bh + boff0 + k0, lB0h);
    gll16(Bl + boff0 + k0, lB0l);
    gll16(Bh + boff1 + k0, lB1h);
    gll16(Bl + boff1 + k0, lB1l);
    __syncthreads();
    short8 ah[4], al[4];
#pragma unroll
    for (int t = 0; t < 4; ++t) {
      int r = wm + t * 16 + l15;
      int sa = (quad ^ ((r >> 1) & 3)) << 3;
      ah[t] = *(const short8*)&Ash[r * 32 + sa];
      if (ALO) al[t] = *(const short8*)&Asl[r * 32 + sa];
    }
#pragma unroll
    for (int nt = 0; nt < 4; ++nt) {
      int rb = wn + nt * 16 + l15;
      int sb = (quad ^ ((rb >> 1) & 3)) << 3;
      short8 bh = *(const short8*)&Bsh[rb * 32 + sb];
      short8 bl = *(const short8*)&Bsl[rb * 32 + sb];
#pragma unroll
      for (int mt = 0; mt < 4; ++mt) {
        acc[mt][nt] = __builtin_amdgcn_mfma_f32_16x16x32_bf16(ah[mt], bh, acc[mt][nt], 0, 0, 0);
        acc[mt][nt] = __builtin_amdgcn_mfma_f32_16x16x32_bf16(ah[mt], bl, acc[mt][nt], 0, 0, 0);
        if (ALO)
          acc[mt][nt] = __builtin_amdgcn_mfma_f32_16x16x32_bf16(al[mt], bh, acc[mt][nt], 0, 0, 0);
      }
    }
  }

  float bv[4];
#pragma unroll
  for (int nt = 0; nt < 4; ++nt) bv[nt] = bias[c0 + wn + nt * 16 + l15];
#pragma unroll
  for (int mt = 0; mt < 4; ++mt) {
#pragma unroll
    for (int r = 0; r < 4; ++r) {
      int gr = r0 + wm + mt * 16 + quad * 4 + r;
      if (gr >= M) continue;
      float osc = SCALE ? oscale[gr] : 1.f;
#pragma unroll
      for (int nt = 0; nt < 4; ++nt) {
        int gc = c0 + wn + nt * 16 + l15;
        float v = acc[mt][nt][r] + bv[nt];
        if (ACT == 1) v = fmaxf(v, 0.f);
        if (ACT == 2) v = (v > 0.f) ? v : 0.01f * v;
        if (SCALE) v *= osc;
        size_t idx = (size_t)gr * Nc + gc;
        if (OUT == 0) {
          ((float*)C0)[idx] = v;
        } else if (OUT == 1) {
          ((ushort*)C0)[idx] = f2bf(v);
        } else {
          ushort hv = f2bf(v);
          ((ushort*)C0)[idx] = hv;
          ((ushort*)C1)[idx] = f2bf(v - bf2f(hv));
        }
      }
    }
  }
}

// ---------------- pooling + tail ----------------
__global__ void k_gbounds(const int* __restrict__ gid, int* __restrict__ gstart) {
  int g = blockIdx.x * blockDim.x + threadIdx.x;
  if (g > NG) return;
  int lo = 0, hi = NN;
  while (lo < hi) {
    int mid = (lo + hi) >> 1;
    if (gid[mid] < g) lo = mid + 1; else hi = mid;
  }
  gstart[g] = lo;
}

__global__ void k_pool(const ushort* __restrict__ xh, const int* __restrict__ gstart,
                       ushort* __restrict__ ph, ushort* __restrict__ pl) {
  int g = blockIdx.x * 4 + (threadIdx.x >> 6);
  if (g >= NG) return;
  int lane = threadIdx.x & 63;
  int beg = gstart[g], end = gstart[g + 1];
  float a0 = 0.f, a1 = 0.f, a2 = 0.f, a3 = 0.f;
  for (int r = beg; r < end; ++r) {
    uint2 u = *(const uint2*)(xh + (size_t)r * DH + lane * 4);
    a0 += __uint_as_float(u.x << 16);
    a1 += __uint_as_float(u.x & 0xffff0000u);
    a2 += __uint_as_float(u.y << 16);
    a3 += __uint_as_float(u.y & 0xffff0000u);
  }
  float inv = 1.f / fmaxf((float)(end - beg), 1.f);
  float o[4] = {a0 * inv, a1 * inv, a2 * inv, a3 * inv};
  ushort4 hv, lv;
  hv.x = f2bf(o[0]); lv.x = f2bf(o[0] - bf2f(hv.x));
  hv.y = f2bf(o[1]); lv.y = f2bf(o[1] - bf2f(hv.y));
  hv.z = f2bf(o[2]); lv.z = f2bf(o[2] - bf2f(hv.z));
  hv.w = f2bf(o[3]); lv.w = f2bf(o[3] - bf2f(hv.w));
  *(ushort4*)(ph + (size_t)g * DH + lane * 4) = hv;
  *(ushort4*)(pl + (size_t)g * DH + lane * 4) = lv;
}

__global__ void k_out(const float* __restrict__ z2, const float* __restrict__ W3,
                      const float* __restrict__ b3, float* __restrict__ out) {
  int g = blockIdx.x * 4 + (threadIdx.x >> 6);
  if (g >= NG) return;
  int lane = threadIdx.x & 63;
  float s = 0.f;
  const float* zr = z2 + (size_t)g * DM2;
  for (int k = lane; k < DM2; k += 64) s += zr[k] * W3[k];
  for (int off = 32; off > 0; off >>= 1) s += __shfl_down(s, off);
  if (lane == 0) out[g] = s + b3[0];
}

// ---------------- launcher ----------------
extern "C" void kernel_launch(void* const* d_in, const int* in_sizes, int n_in,
                              void* d_out, int out_size, void* d_ws, size_t ws_size,
                              hipStream_t stream) {
  (void)in_sizes; (void)n_in; (void)out_size; (void)ws_size;
  const float* h     = (const float*)d_in[0];
  const int*   src   = (const int*)d_in[1];
  const int*   dst   = (const int*)d_in[2];
  const int*   gid   = (const int*)d_in[3];
  const float* W_in  = (const float*)d_in[4];
  const float* b_in  = (const float*)d_in[5];
  const float* W_gcr = (const float*)d_in[6];
  const float* b_gcr = (const float*)d_in[7];
  const float* W1    = (const float*)d_in[8];
  const float* b1    = (const float*)d_in[9];
  const float* W2    = (const float*)d_in[10];
  const float* b2    = (const float*)d_in[11];
  const float* W3    = (const float*)d_in[12];
  const float* b3    = (const float*)d_in[13];
  float* out = (float*)d_out;

  char* p = (char*)d_ws;
  auto alloc = [&](size_t bytes) {
    char* q = p;
    p += (bytes + 255) & ~(size_t)255;
    return q;
  };
  int*    outdeg = (int*)alloc((size_t)NN * 4);
  int*    indeg  = (int*)alloc((size_t)NN * 4);
  float*  onorm  = (float*)alloc((size_t)NN * 4);
  float*  inorm  = (float*)alloc((size_t)NN * 4);
  int*    incl   = (int*)alloc((size_t)NN * 4);
  int*    bsum   = (int*)alloc(128 * 4);
  int*    offs   = (int*)alloc((size_t)(NN + 1) * 4);
  int*    cursor = (int*)alloc((size_t)NN * 4);
  int*    ssrc   = (int*)alloc((size_t)NE * 4);
  int*    gstart = (int*)alloc((size_t)(NG + 1) * 4);
  uint*   hb     = (uint*)alloc((size_t)NN * 48 * 4);
  ushort* xh0    = (ushort*)alloc((size_t)NN * DH * 2);
  ushort* xh1    = (ushort*)alloc((size_t)NN * DH * 2);
  ushort* Ah1    = (ushort*)alloc((size_t)NN * DH * 2);
  ushort* A0h    = (ushort*)alloc((size_t)NN * KPAD * 2);
  ushort* A0l    = (ushort*)alloc((size_t)NN * KPAD * 2);
  ushort* Wt0h   = (ushort*)alloc((size_t)256 * KPAD * 2);
  ushort* Wt0l   = (ushort*)alloc((size_t)256 * KPAD * 2);
  ushort* Wtgh   = (ushort*)alloc((size_t)10 * 65536 * 2);
  ushort* Wtgl   = (ushort*)alloc((size_t)10 * 65536 * 2);
  ushort* Wt1h   = (ushort*)alloc((size_t)DM1 * DH * 2);
  ushort* Wt1l   = (ushort*)alloc((size_t)DM1 * DH * 2);
  ushort* Wt2h   = (ushort*)alloc((size_t)DM2 * DM1 * 2);
  ushort* Wt2l   = (ushort*)alloc((size_t)DM2 * DM1 * 2);
  ushort* plh    = (ushort*)alloc((size_t)NG * DH * 2);
  ushort* pll    = (ushort*)alloc((size_t)NG * DH * 2);
  ushort* z1h    = (ushort*)alloc((size_t)NG * DM1 * 2);
  ushort* z1l    = (ushort*)alloc((size_t)NG * DM1 * 2);
  float*  z2     = (float*)alloc((size_t)NG * DM2 * 4);

  hipMemsetAsync(outdeg, 0, (size_t)NN * 4, stream);
  hipMemsetAsync(indeg, 0, (size_t)NN * 4, stream);
  k_deg<<<(NE + 255) / 256, 256, 0, stream>>>(src, dst, outdeg, indeg);
  k_norm<<<(NN + 255) / 256, 256, 0, stream>>>(outdeg, indeg, onorm, inorm);
  int nb = (NN + 1023) / 1024;
  k_scan_block<<<nb, 1024, 0, stream>>>(indeg, incl, bsum, NN);
  k_scan_sums<<<1, 64, 0, stream>>>(bsum, nb);
  k_scan_add<<<(NN + 255) / 256, 256, 0, stream>>>(incl, bsum, indeg, offs, cursor, NN);
  k_scatter<<<(NE + 255) / 256, 256, 0, stream>>>(src, dst, cursor, ssrc);

  const int nconv = 256 * KPAD + 10 * 65536 + DM1 * DH + DM2 * DM1;
  k_convw<<<(nconv + 255) / 256, 256, 0, stream>>>(W_in, W_gcr, W1, W2,
                                                   Wt0h, Wt0l, Wtgh, Wtgl,
                                                   Wt1h, Wt1l, Wt2h, Wt2l);
  k_conv_h<<<(NN * 48 + 255) / 256, 256, 0, stream>>>(h, onorm, hb);

  // input conv: gather pre-scaled bf16 h (pad 96), hi/lo GEMM 96->256, no act,
  // output bf16-hi pre-scaled by onorm (ready for next gather)
  k_spmm74<<<(NN + 3) / 4, 256, 0, stream>>>(hb, offs, ssrc, inorm, A0h, A0l);
  dim3 gmm((NN + 127) / 128, 1);
  k_mfma<0, 1, 1, 1><<<gmm, 512, 0, stream>>>(A0h, A0l, Wt0h, Wt0l, b_in, onorm,
                                              xh0, nullptr, NN, KPAD, DH);

  // 10 conv layers: gather -> A-hi plane -> 2-term MFMA GEMM + relu.
  // Layers 0..8 output pre-scaled by onorm; layer 9 unscaled for pooling.
  ushort* xin = xh0;
  ushort* xout = xh1;
  for (int li = 0; li < 10; ++li) {
    k_spmm1<<<(NN + 3) / 4, 256, 0, stream>>>(xin, offs, ssrc, inorm, Ah1);
    const ushort* bh = Wtgh + (size_t)li * 65536;
    const ushort* bl = Wtgl + (size_t)li * 65536;
    const float* bb = b_gcr + li * 256;
    if (li < 9)
      k_mfma<1, 1, 1, 0><<<gmm, 512, 0, stream>>>(Ah1, nullptr, bh, bl, bb, onorm,
                                                  xout, nullptr, NN, DH, DH);
    else
      k_mfma<1, 1, 0, 0><<<gmm, 512, 0, stream>>>(Ah1, nullptr, bh, bl, bb, nullptr,
                                                  xout, nullptr, NN, DH, DH);
    ushort* t = xin; xin = xout; xout = t;
  }

  k_gbounds<<<(NG + 1 + 255) / 256, 256, 0, stream>>>(gid, gstart);
  k_pool<<<(NG + 3) / 4, 256, 0, stream>>>(xin, gstart, plh, pll);

  dim3 gt1(NG / 128, DM1 / 256);
  k_mfma<2, 2, 0, 1><<<gt1, 512, 0, stream>>>(plh, pll, Wt1h, Wt1l, b1, nullptr,
                                              z1h, z1l, NG, DH, DM1);
  dim3 gt2(NG / 128, DM2 / 256);
  k_mfma<2, 0, 0, 1><<<gt2, 512, 0, stream>>>(z1h, z1l, Wt2h, Wt2l, b2, nullptr,
                                              z2, nullptr, NG, DM1, DM2);
  k_out<<<(NG + 3) / 4, 256, 0, stream>>>(z2, W3, b3, out);
}

// Round 11
// 1542.922 us; speedup vs baseline: 3.5003x; 1.1002x over previous
//
#include <hip/hip_runtime.h>
#include <hip/hip_bf16.h>

#define NN 100000
#define NE 800000
#define NG 2048
#define DIN 74
#define KPAD 96
#define DH 256
#define DM1 1024
#define DM2 512

typedef __attribute__((ext_vector_type(8))) short short8;
typedef __attribute__((ext_vector_type(4))) float f32x4;

__device__ inline ushort f2bf(float f) {
  unsigned u = __float_as_uint(f);
  return (ushort)((u + 0x7fffu + ((u >> 16) & 1u)) >> 16);
}
__device__ inline float bf2f(ushort h) { return __uint_as_float(((unsigned)h) << 16); }

// async 16B/lane global->LDS: lds dest is wave-uniform base + lane*16
__device__ inline void gll16(const ushort* g, ushort* l) {
  __builtin_amdgcn_global_load_lds((const __attribute__((address_space(1))) void*)g,
                                   (__attribute__((address_space(3))) void*)l, 16, 0, 0);
}

// ---------------- degrees & norms ----------------
__global__ void k_deg(const int* __restrict__ src, const int* __restrict__ dst,
                      int* __restrict__ outd, int* __restrict__ ind) {
  int e = blockIdx.x * blockDim.x + threadIdx.x;
  if (e < NE) {
    atomicAdd(&outd[src[e]], 1);
    atomicAdd(&ind[dst[e]], 1);
  }
}

__global__ void k_norm(const int* __restrict__ outd, const int* __restrict__ ind,
                       float* __restrict__ onorm, float* __restrict__ inorm) {
  int i = blockIdx.x * blockDim.x + threadIdx.x;
  if (i < NN) {
    onorm[i] = rsqrtf(fmaxf((float)outd[i], 1.f));
    inorm[i] = rsqrtf(fmaxf((float)ind[i], 1.f));
  }
}

// ---------------- CSR build (scan + counting sort) ----------------
__global__ void k_scan_block(const int* __restrict__ deg, int* __restrict__ incl,
                             int* __restrict__ bsum, int n) {
  __shared__ int s[1024];
  int t = threadIdx.x;
  int i = blockIdx.x * 1024 + t;
  int v = (i < n) ? deg[i] : 0;
  s[t] = v;
  __syncthreads();
  for (int off = 1; off < 1024; off <<= 1) {
    int x = (t >= off) ? s[t - off] : 0;
    __syncthreads();
    s[t] += x;
    __syncthreads();
  }
  if (i < n) incl[i] = s[t];
  if (t == 1023) bsum[blockIdx.x] = s[1023];
}

// single-wave exclusive scan of block sums (nb <= 128)
__global__ void k_scan_sums(int* bsum, int nb) {
  int lane = threadIdx.x & 63;
  int i0 = 2 * lane, i1 = 2 * lane + 1;
  int v0 = (i0 < nb) ? bsum[i0] : 0;
  int v1 = (i1 < nb) ? bsum[i1] : 0;
  int s = v0 + v1;
  for (int off = 1; off < 64; off <<= 1) {
    int t = __shfl_up(s, off);
    if (lane >= off) s += t;
  }
  int excl = s - (v0 + v1);
  if (i0 < nb) bsum[i0] = excl;
  if (i1 < nb) bsum[i1] = excl + v0;
}

__global__ void k_scan_add(const int* __restrict__ incl, const int* __restrict__ bsum,
                           const int* __restrict__ deg,
                           int* __restrict__ offs, int* __restrict__ cursor, int n) {
  int i = blockIdx.x * blockDim.x + threadIdx.x;
  if (i < n) {
    int v = incl[i] + bsum[i >> 10];
    offs[i + 1] = v;
    cursor[i] = v - deg[i];
    if (i == 0) offs[0] = 0;
  }
}

__global__ void k_scatter(const int* __restrict__ src, const int* __restrict__ dst,
                          int* __restrict__ cursor, int* __restrict__ ssrc) {
  int e = blockIdx.x * blockDim.x + threadIdx.x;
  if (e < NE) {
    int pos = atomicAdd(&cursor[dst[e]], 1);
    ssrc[pos] = src[e];
  }
}

// ---------------- weight convert: fp32 [k][n] -> bf16 hi/lo planes [n][k] ----------------
__global__ void k_convw(const float* __restrict__ W_in, const float* __restrict__ W_gcr,
                        const float* __restrict__ W1, const float* __restrict__ W2,
                        ushort* __restrict__ Wt0h, ushort* __restrict__ Wt0l,
                        ushort* __restrict__ Wtgh, ushort* __restrict__ Wtgl,
                        ushort* __restrict__ Wt1h, ushort* __restrict__ Wt1l,
                        ushort* __restrict__ Wt2h, ushort* __restrict__ Wt2l) {
  int idx = blockIdx.x * blockDim.x + threadIdx.x;
  const int n0 = 256 * KPAD;
  const int n1 = n0 + 10 * 65536;
  const int n2 = n1 + DM1 * DH;
  const int n3 = n2 + DM2 * DM1;
  float v;
  ushort *dh, *dl;
  int o;
  if (idx < n0) {
    int n = idx / KPAD, k = idx - n * KPAD;
    v = (k < DIN) ? W_in[k * DH + n] : 0.f;
    dh = Wt0h; dl = Wt0l; o = idx;
  } else if (idx < n1) {
    int j = idx - n0;
    int l = j >> 16, r = j & 65535;
    int n = r >> 8, k = r & 255;
    v = W_gcr[l * 65536 + k * 256 + n];
    dh = Wtgh; dl = Wtgl; o = l * 65536 + n * 256 + k;
  } else if (idx < n2) {
    int j = idx - n1;
    int n = j >> 8, k = j & 255;
    v = W1[k * DM1 + n];
    dh = Wt1h; dl = Wt1l; o = n * 256 + k;
  } else if (idx < n3) {
    int j = idx - n2;
    int n = j >> 10, k = j & 1023;
    v = W2[k * DM2 + n];
    dh = Wt2h; dl = Wt2l; o = n * 1024 + k;
  } else {
    return;
  }
  ushort hv = f2bf(v);
  dh[o] = hv;
  dl[o] = f2bf(v - bf2f(hv));
}

// ---------------- input features: fp32 [N][74] -> bf16*onorm packed [N][48] uints ----------------
__global__ void k_conv_h(const float* __restrict__ h, const float* __restrict__ onorm,
                         uint* __restrict__ hb) {
  int idx = blockIdx.x * blockDim.x + threadIdx.x;
  if (idx >= NN * 48) return;
  int r = idx / 48, j = idx - r * 48;
  float s = onorm[r];
  int k0 = j * 2;
  float v0 = (k0 < DIN) ? h[(size_t)r * DIN + k0] * s : 0.f;
  float v1 = (k0 + 1 < DIN) ? h[(size_t)r * DIN + k0 + 1] * s : 0.f;
  hb[idx] = (uint)f2bf(v0) | ((uint)f2bf(v1) << 16);
}

// ---------------- input SpMM: gather pre-scaled bf16 h rows (48 uints), depth-4 ----------------
__global__ void k_spmm74(const uint* __restrict__ hb, const int* __restrict__ offs,
                         const int* __restrict__ ssrc, const float* __restrict__ inorm,
                         ushort* __restrict__ Ahi, ushort* __restrict__ Alo) {
  int row = blockIdx.x * 4 + (threadIdx.x >> 6);
  if (row >= NN) return;
  int lane = threadIdx.x & 63;
  int beg = offs[row], n = offs[row + 1] - beg;
  bool act = lane < 48;
  const uint* xb = hb + lane;
  float a0 = 0.f, a1 = 0.f;
  uint d0 = 0, d1 = 0, d2 = 0, d3 = 0;
#define LJ74(dj, e) { dj = 0; if (act && (e) < n) dj = xb[(size_t)ssrc[beg + (e)] * 48]; }
  LJ74(d0, 0)
  LJ74(d1, 1)
  LJ74(d2, 2)
  LJ74(d3, 3)
  int e = 0;
#define STEP74(dj) { uint u = dj; LJ74(dj, e + 4) \
    a0 += __uint_as_float(u << 16); a1 += __uint_as_float(u & 0xffff0000u); ++e; }
  while (e < n) {
    STEP74(d0) if (e >= n) break;
    STEP74(d1) if (e >= n) break;
    STEP74(d2) if (e >= n) break;
    STEP74(d3)
  }
#undef STEP74
#undef LJ74
  float win = inorm[row];
  float v0 = a0 * win, v1 = a1 * win;
  ushort h0 = f2bf(v0), h1 = f2bf(v1);
  ushort l0 = f2bf(v0 - bf2f(h0)), l1 = f2bf(v1 - bf2f(h1));
  if (act) {
    *(uint*)&Ahi[(size_t)row * KPAD + lane * 2] = (uint)h0 | ((uint)h1 << 16);
    *(uint*)&Alo[(size_t)row * KPAD + lane * 2] = (uint)l0 | ((uint)l1 << 16);
  }
}

// ---------------- conv SpMM: 2 rows per wave (half-wave per row, 16B/lane), depth-4 ----------------
// gathers bf16-hi pre-scaled x, writes single bf16-hi A plane. Predicated loads (no
// traffic on masked lanes); loop trip = max(deg(r0),deg(r1)) wave-uniform.
__global__ void k_spmm1(const ushort* __restrict__ xin, const int* __restrict__ offs,
                        const int* __restrict__ ssrc, const float* __restrict__ inorm,
                        ushort* __restrict__ Ah) {
  int wid = blockIdx.x * 4 + (threadIdx.x >> 6);
  int rbase = wid * 2;
  if (rbase >= NN) return;  // NN even: rbase+1 valid whenever rbase is
  int lane = threadIdx.x & 63;
  int l5 = lane & 31;
  int row = rbase + (lane >> 5);
  int beg = offs[row], n = offs[row + 1] - beg;
  int nmax = max(n, __shfl_xor(n, 32));
  const ushort* xb = xin + l5 * 8;  // 16B per lane, 32 lanes cover 512B row
  float a0 = 0.f, a1 = 0.f, a2 = 0.f, a3 = 0.f;
  float a4 = 0.f, a5 = 0.f, a6 = 0.f, a7 = 0.f;
  uint4 z = {0, 0, 0, 0};
  uint4 d0 = z, d1 = z, d2 = z, d3 = z;
#define LJ(dj, e) { dj = z; if ((e) < n) \
    dj = *(const uint4*)(xb + (size_t)ssrc[beg + (e)] * DH); }
  LJ(d0, 0)
  LJ(d1, 1)
  LJ(d2, 2)
  LJ(d3, 3)
  int e = 0;
#define STEP(dj) { uint4 u = dj; LJ(dj, e + 4) \
    a0 += __uint_as_float(u.x << 16); a1 += __uint_as_float(u.x & 0xffff0000u); \
    a2 += __uint_as_float(u.y << 16); a3 += __uint_as_float(u.y & 0xffff0000u); \
    a4 += __uint_as_float(u.z << 16); a5 += __uint_as_float(u.z & 0xffff0000u); \
    a6 += __uint_as_float(u.w << 16); a7 += __uint_as_float(u.w & 0xffff0000u); ++e; }
  while (e < nmax) {
    STEP(d0) if (e >= nmax) break;
    STEP(d1) if (e >= nmax) break;
    STEP(d2) if (e >= nmax) break;
    STEP(d3)
  }
#undef STEP
#undef LJ
  float win = inorm[row];
  uint4 o;
  o.x = (uint)f2bf(a0 * win) | ((uint)f2bf(a1 * win) << 16);
  o.y = (uint)f2bf(a2 * win) | ((uint)f2bf(a3 * win) << 16);
  o.z = (uint)f2bf(a4 * win) | ((uint)f2bf(a5 * win) << 16);
  o.w = (uint)f2bf(a6 * win) | ((uint)f2bf(a7 * win) << 16);
  *(uint4*)(Ah + (size_t)row * DH + l5 * 8) = o;
}

// ---------------- async-staged bf16 MFMA GEMM ----------------
// A: bf16-hi plane [M][K] (+ optional lo plane when ALO=1); B: hi/lo planes [N][K].
// Staging via global_load_lds (16B/lane). XOR chunk swizzle -> free 2-way frag reads.
// ACT: 0=none 1=relu 2=leaky(0.01). OUT: 0=fp32 C0, 1=bf16 hi C0, 2=planes C0/C1
// SCALE: multiply output by oscale[row] (after ACT). ALO: A lo-plane present (3 vs 2 MFMA).
template <int ACT, int OUT, int SCALE, int ALO>
__global__ __launch_bounds__(512, 4) void k_mfma(
    const ushort* __restrict__ Ah, const ushort* __restrict__ Al,
    const ushort* __restrict__ Bh, const ushort* __restrict__ Bl,
    const float* __restrict__ bias, const float* __restrict__ oscale,
    void* __restrict__ C0, void* __restrict__ C1,
    int M, int K, int Nc) {
  __shared__ __align__(16) ushort Ash[128 * 32];
  __shared__ __align__(16) ushort Asl[ALO ? 128 * 32 : 8];
  __shared__ __align__(16) ushort Bsh[256 * 32], Bsl[256 * 32];
  const int tid = threadIdx.x, lane = tid & 63, wv = tid >> 6;
  const int wm = (wv >> 2) * 64, wn = (wv & 3) * 64;
  const int quad = lane >> 4, l15 = lane & 15;
  const int r0 = blockIdx.x * 128, c0 = blockIdx.y * 256;

  const int srow = lane >> 2, clds = lane & 3;
  const int arow = 16 * wv + srow;
  const int acg = clds ^ ((arow >> 1) & 3);
  int agr = r0 + arow;
  if (agr > M - 1) agr = M - 1;  // clamp; epilogue masks stores
  const size_t aoff = (size_t)agr * K + acg * 8;
  const int brow0 = 16 * wv + srow, brow1 = brow0 + 128;
  const int bcg0 = clds ^ ((brow0 >> 1) & 3);
  const int bcg1 = clds ^ ((brow1 >> 1) & 3);
  const size_t boff0 = (size_t)(c0 + brow0) * K + bcg0 * 8;
  const size_t boff1 = (size_t)(c0 + brow1) * K + bcg1 * 8;
  ushort* lAh = &Ash[(16 * wv) * 32];
  ushort* lAl = &Asl[ALO ? (16 * wv) * 32 : 0];
  ushort* lB0h = &Bsh[(16 * wv) * 32];
  ushort* lB0l = &Bsl[(16 * wv) * 32];
  ushort* lB1h = &Bsh[(16 * wv + 128) * 32];
  ushort* lB1l = &Bsl[(16 * wv + 128) * 32];

  f32x4 acc[4][4] = {};
  const int nk = K >> 5;
  for (int s = 0; s < nk; ++s) {
    const int k0 = s << 5;
    __syncthreads();
    gll16(Ah + aoff + k0, lAh);
    if (ALO) gll16(Al + aoff + k0, lAl);
    gll16(Bh + boff0 + k0, lB0h);
    gll16(Bl + boff0 + k0, lB0l);
    gll16(Bh + boff1 + k0, lB1h);
    gll16(Bl + boff1 + k0, lB1l);
    __syncthreads();
    short8 ah[4], al[4];
#pragma unroll
    for (int t = 0; t < 4; ++t) {
      int r = wm + t * 16 + l15;
      int sa = (quad ^ ((r >> 1) & 3)) << 3;
      ah[t] = *(const short8*)&Ash[r * 32 + sa];
      if (ALO) al[t] = *(const short8*)&Asl[r * 32 + sa];
    }
#pragma unroll
    for (int nt = 0; nt < 4; ++nt) {
      int rb = wn + nt * 16 + l15;
      int sb = (quad ^ ((rb >> 1) & 3)) << 3;
      short8 bh = *(const short8*)&Bsh[rb * 32 + sb];
      short8 bl = *(const short8*)&Bsl[rb * 32 + sb];
#pragma unroll
      for (int mt = 0; mt < 4; ++mt) {
        acc[mt][nt] = __builtin_amdgcn_mfma_f32_16x16x32_bf16(ah[mt], bh, acc[mt][nt], 0, 0, 0);
        acc[mt][nt] = __builtin_amdgcn_mfma_f32_16x16x32_bf16(ah[mt], bl, acc[mt][nt], 0, 0, 0);
        if (ALO)
          acc[mt][nt] = __builtin_amdgcn_mfma_f32_16x16x32_bf16(al[mt], bh, acc[mt][nt], 0, 0, 0);
      }
    }
  }

  float bv[4];
#pragma unroll
  for (int nt = 0; nt < 4; ++nt) bv[nt] = bias[c0 + wn + nt * 16 + l15];
#pragma unroll
  for (int mt = 0; mt < 4; ++mt) {
#pragma unroll
    for (int r = 0; r < 4; ++r) {
      int gr = r0 + wm + mt * 16 + quad * 4 + r;
      if (gr >= M) continue;
      float osc = SCALE ? oscale[gr] : 1.f;
#pragma unroll
      for (int nt = 0; nt < 4; ++nt) {
        int gc = c0 + wn + nt * 16 + l15;
        float v = acc[mt][nt][r] + bv[nt];
        if (ACT == 1) v = fmaxf(v, 0.f);
        if (ACT == 2) v = (v > 0.f) ? v : 0.01f * v;
        if (SCALE) v *= osc;
        size_t idx = (size_t)gr * Nc + gc;
        if (OUT == 0) {
          ((float*)C0)[idx] = v;
        } else if (OUT == 1) {
          ((ushort*)C0)[idx] = f2bf(v);
        } else {
          ushort hv = f2bf(v);
          ((ushort*)C0)[idx] = hv;
          ((ushort*)C1)[idx] = f2bf(v - bf2f(hv));
        }
      }
    }
  }
}

// ---------------- pooling + tail ----------------
__global__ void k_gbounds(const int* __restrict__ gid, int* __restrict__ gstart) {
  int g = blockIdx.x * blockDim.x + threadIdx.x;
  if (g > NG) return;
  int lo = 0, hi = NN;
  while (lo < hi) {
    int mid = (lo + hi) >> 1;
    if (gid[mid] < g) lo = mid + 1; else hi = mid;
  }
  gstart[g] = lo;
}

__global__ void k_pool(const ushort* __restrict__ xh, const int* __restrict__ gstart,
                       ushort* __restrict__ ph, ushort* __restrict__ pl) {
  int g = blockIdx.x * 4 + (threadIdx.x >> 6);
  if (g >= NG) return;
  int lane = threadIdx.x & 63;
  int beg = gstart[g], end = gstart[g + 1];
  float a0 = 0.f, a1 = 0.f, a2 = 0.f, a3 = 0.f;
  for (int r = beg; r < end; ++r) {
    uint2 u = *(const uint2*)(xh + (size_t)r * DH + lane * 4);
    a0 += __uint_as_float(u.x << 16);
    a1 += __uint_as_float(u.x & 0xffff0000u);
    a2 += __uint_as_float(u.y << 16);
    a3 += __uint_as_float(u.y & 0xffff0000u);
  }
  float inv = 1.f / fmaxf((float)(end - beg), 1.f);
  float o[4] = {a0 * inv, a1 * inv, a2 * inv, a3 * inv};
  ushort4 hv, lv;
  hv.x = f2bf(o[0]); lv.x = f2bf(o[0] - bf2f(hv.x));
  hv.y = f2bf(o[1]); lv.y = f2bf(o[1] - bf2f(hv.y));
  hv.z = f2bf(o[2]); lv.z = f2bf(o[2] - bf2f(hv.z));
  hv.w = f2bf(o[3]); lv.w = f2bf(o[3] - bf2f(hv.w));
  *(ushort4*)(ph + (size_t)g * DH + lane * 4) = hv;
  *(ushort4*)(pl + (size_t)g * DH + lane * 4) = lv;
}

__global__ void k_out(const float* __restrict__ z2, const float* __restrict__ W3,
                      const float* __restrict__ b3, float* __restrict__ out) {
  int g = blockIdx.x * 4 + (threadIdx.x >> 6);
  if (g >= NG) return;
  int lane = threadIdx.x & 63;
  float s = 0.f;
  const float* zr = z2 + (size_t)g * DM2;
  for (int k = lane; k < DM2; k += 64) s += zr[k] * W3[k];
  for (int off = 32; off > 0; off >>= 1) s += __shfl_down(s, off);
  if (lane == 0) out[g] = s + b3[0];
}

// ---------------- launcher ----------------
extern "C" void kernel_launch(void* const* d_in, const int* in_sizes, int n_in,
                              void* d_out, int out_size, void* d_ws, size_t ws_size,
                              hipStream_t stream) {
  (void)in_sizes; (void)n_in; (void)out_size; (void)ws_size;
  const float* h     = (const float*)d_in[0];
  const int*   src   = (const int*)d_in[1];
  const int*   dst   = (const int*)d_in[2];
  const int*   gid   = (const int*)d_in[3];
  const float* W_in  = (const float*)d_in[4];
  const float* b_in  = (const float*)d_in[5];
  const float* W_gcr = (const float*)d_in[6];
  const float* b_gcr = (const float*)d_in[7];
  const float* W1    = (const float*)d_in[8];
  const float* b1    = (const float*)d_in[9];
  const float* W2    = (const float*)d_in[10];
  const float* b2    = (const float*)d_in[11];
  const float* W3    = (const float*)d_in[12];
  const float* b3    = (const float*)d_in[13];
  float* out = (float*)d_out;

  char* p = (char*)d_ws;
  auto alloc = [&](size_t bytes) {
    char* q = p;
    p += (bytes + 255) & ~(size_t)255;
    return q;
  };
  int*    outdeg = (int*)alloc((size_t)NN * 4);
  int*    indeg  = (int*)alloc((size_t)NN * 4);
  float*  onorm  = (float*)alloc((size_t)NN * 4);
  float*  inorm  = (float*)alloc((size_t)NN * 4);
  int*    incl   = (int*)alloc((size_t)NN * 4);
  int*    bsum   = (int*)alloc(128 * 4);
  int*    offs   = (int*)alloc((size_t)(NN + 1) * 4);
  int*    cursor = (int*)alloc((size_t)NN * 4);
  int*    ssrc   = (int*)alloc((size_t)NE * 4);
  int*    gstart = (int*)alloc((size_t)(NG + 1) * 4);
  uint*   hb     = (uint*)alloc((size_t)NN * 48 * 4);
  ushort* xh0    = (ushort*)alloc((size_t)NN * DH * 2);
  ushort* xh1    = (ushort*)alloc((size_t)NN * DH * 2);
  ushort* Ah1    = (ushort*)alloc((size_t)NN * DH * 2);
  ushort* A0h    = (ushort*)alloc((size_t)NN * KPAD * 2);
  ushort* A0l    = (ushort*)alloc((size_t)NN * KPAD * 2);
  ushort* Wt0h   = (ushort*)alloc((size_t)256 * KPAD * 2);
  ushort* Wt0l   = (ushort*)alloc((size_t)256 * KPAD * 2);
  ushort* Wtgh   = (ushort*)alloc((size_t)10 * 65536 * 2);
  ushort* Wtgl   = (ushort*)alloc((size_t)10 * 65536 * 2);
  ushort* Wt1h   = (ushort*)alloc((size_t)DM1 * DH * 2);
  ushort* Wt1l   = (ushort*)alloc((size_t)DM1 * DH * 2);
  ushort* Wt2h   = (ushort*)alloc((size_t)DM2 * DM1 * 2);
  ushort* Wt2l   = (ushort*)alloc((size_t)DM2 * DM1 * 2);
  ushort* plh    = (ushort*)alloc((size_t)NG * DH * 2);
  ushort* pll    = (ushort*)alloc((size_t)NG * DH * 2);
  ushort* z1h    = (ushort*)alloc((size_t)NG * DM1 * 2);
  ushort* z1l    = (ushort*)alloc((size_t)NG * DM1 * 2);
  float*  z2     = (float*)alloc((size_t)NG * DM2 * 4);

  hipMemsetAsync(outdeg, 0, (size_t)NN * 4, stream);
  hipMemsetAsync(indeg, 0, (size_t)NN * 4, stream);
  k_deg<<<(NE + 255) / 256, 256, 0, stream>>>(src, dst, outdeg, indeg);
  k_norm<<<(NN + 255) / 256, 256, 0, stream>>>(outdeg, indeg, onorm, inorm);
  int nb = (NN + 1023) / 1024;
  k_scan_block<<<nb, 1024, 0, stream>>>(indeg, incl, bsum, NN);
  k_scan_sums<<<1, 64, 0, stream>>>(bsum, nb);
  k_scan_add<<<(NN + 255) / 256, 256, 0, stream>>>(incl, bsum, indeg, offs, cursor, NN);
  k_scatter<<<(NE + 255) / 256, 256, 0, stream>>>(src, dst, cursor, ssrc);

  const int nconv = 256 * KPAD + 10 * 65536 + DM1 * DH + DM2 * DM1;
  k_convw<<<(nconv + 255) / 256, 256, 0, stream>>>(W_in, W_gcr, W1, W2,
                                                   Wt0h, Wt0l, Wtgh, Wtgl,
                                                   Wt1h, Wt1l, Wt2h, Wt2l);
  k_conv_h<<<(NN * 48 + 255) / 256, 256, 0, stream>>>(h, onorm, hb);

  // input conv: gather pre-scaled bf16 h (pad 96), hi/lo GEMM 96->256, no act,
  // output bf16-hi pre-scaled by onorm (ready for next gather)
  k_spmm74<<<(NN + 3) / 4, 256, 0, stream>>>(hb, offs, ssrc, inorm, A0h, A0l);
  dim3 gmm((NN + 127) / 128, 1);
  k_mfma<0, 1, 1, 1><<<gmm, 512, 0, stream>>>(A0h, A0l, Wt0h, Wt0l, b_in, onorm,
                                              xh0, nullptr, NN, KPAD, DH);

  // 10 conv layers: 2-row/wave gather -> A-hi plane -> 2-term MFMA GEMM + relu.
  // Layers 0..8 output pre-scaled by onorm; layer 9 unscaled for pooling.
  ushort* xin = xh0;
  ushort* xout = xh1;
  for (int li = 0; li < 10; ++li) {
    k_spmm1<<<(NN + 7) / 8, 256, 0, stream>>>(xin, offs, ssrc, inorm, Ah1);
    const ushort* bh = Wtgh + (size_t)li * 65536;
    const ushort* bl = Wtgl + (size_t)li * 65536;
    const float* bb = b_gcr + li * 256;
    if (li < 9)
      k_mfma<1, 1, 1, 0><<<gmm, 512, 0, stream>>>(Ah1, nullptr, bh, bl, bb, onorm,
                                                  xout, nullptr, NN, DH, DH);
    else
      k_mfma<1, 1, 0, 0><<<gmm, 512, 0, stream>>>(Ah1, nullptr, bh, bl, bb, nullptr,
                                                  xout, nullptr, NN, DH, DH);
    ushort* t = xin; xin = xout; xout = t;
  }

  k_gbounds<<<(NG + 1 + 255) / 256, 256, 0, stream>>>(gid, gstart);
  k_pool<<<(NG + 3) / 4, 256, 0, stream>>>(xin, gstart, plh, pll);

  dim3 gt1(NG / 128, DM1 / 256);
  k_mfma<2, 2, 0, 1><<<gt1, 512, 0, stream>>>(plh, pll, Wt1h, Wt1l, b1, nullptr,
                                              z1h, z1l, NG, DH, DM1);
  dim3 gt2(NG / 128, DM2 / 256);
  k_mfma<2, 0, 0, 1><<<gt2, 512, 0, stream>>>(z1h, z1l, Wt2h, Wt2l, b2, nullptr,
                                              z2, nullptr, NG, DM1, DM2);
  k_out<<<(NG + 3) / 4, 256, 0, stream>>>(z2, W3, b3, out);
}

// Round 12
// 1494.612 us; speedup vs baseline: 3.6135x; 1.0323x over previous
//
#include <hip/hip_runtime.h>
#include <hip/hip_bf16.h>

#define NN 100000
#define NE 800000
#define NG 2048
#define DIN 74
#define KPAD 96
#define DH 256
#define DM1 1024
#define DM2 512

typedef __attribute__((ext_vector_type(8))) short short8;
typedef __attribute__((ext_vector_type(4))) float f32x4;

__device__ inline ushort f2bf(float f) {
  unsigned u = __float_as_uint(f);
  return (ushort)((u + 0x7fffu + ((u >> 16) & 1u)) >> 16);
}
__device__ inline float bf2f(ushort h) { return __uint_as_float(((unsigned)h) << 16); }

// async 16B/lane global->LDS: lds dest is wave-uniform base + lane*16
__device__ inline void gll16(const ushort* g, ushort* l) {
  __builtin_amdgcn_global_load_lds((const __attribute__((address_space(1))) void*)g,
                                   (__attribute__((address_space(3))) void*)l, 16, 0, 0);
}

// ---------------- degrees ----------------
__global__ void k_deg(const int* __restrict__ src, const int* __restrict__ dst,
                      int* __restrict__ outd, int* __restrict__ ind) {
  int e = blockIdx.x * blockDim.x + threadIdx.x;
  if (e < NE) {
    atomicAdd(&outd[src[e]], 1);
    atomicAdd(&ind[dst[e]], 1);
  }
}

// ---------------- CSR build (scan + counting sort) ----------------
__global__ void k_scan_block(const int* __restrict__ deg, int* __restrict__ incl,
                             int* __restrict__ bsum, int n) {
  __shared__ int s[1024];
  int t = threadIdx.x;
  int i = blockIdx.x * 1024 + t;
  int v = (i < n) ? deg[i] : 0;
  s[t] = v;
  __syncthreads();
  for (int off = 1; off < 1024; off <<= 1) {
    int x = (t >= off) ? s[t - off] : 0;
    __syncthreads();
    s[t] += x;
    __syncthreads();
  }
  if (i < n) incl[i] = s[t];
  if (t == 1023) bsum[blockIdx.x] = s[1023];
}

// single-wave exclusive scan of block sums (nb <= 128)
__global__ void k_scan_sums(int* bsum, int nb) {
  int lane = threadIdx.x & 63;
  int i0 = 2 * lane, i1 = 2 * lane + 1;
  int v0 = (i0 < nb) ? bsum[i0] : 0;
  int v1 = (i1 < nb) ? bsum[i1] : 0;
  int s = v0 + v1;
  for (int off = 1; off < 64; off <<= 1) {
    int t = __shfl_up(s, off);
    if (lane >= off) s += t;
  }
  int excl = s - (v0 + v1);
  if (i0 < nb) bsum[i0] = excl;
  if (i1 < nb) bsum[i1] = excl + v0;
}

// scan finalize + norms (merged k_norm)
__global__ void k_scan_add(const int* __restrict__ incl, const int* __restrict__ bsum,
                           const int* __restrict__ indeg, const int* __restrict__ outdeg,
                           int* __restrict__ offs, int* __restrict__ cursor,
                           float* __restrict__ onorm, float* __restrict__ inorm, int n) {
  int i = blockIdx.x * blockDim.x + threadIdx.x;
  if (i < n) {
    int v = incl[i] + bsum[i >> 10];
    offs[i + 1] = v;
    cursor[i] = v - indeg[i];
    if (i == 0) offs[0] = 0;
    onorm[i] = rsqrtf(fmaxf((float)outdeg[i], 1.f));
    inorm[i] = rsqrtf(fmaxf((float)indeg[i], 1.f));
  }
}

__global__ void k_scatter(const int* __restrict__ src, const int* __restrict__ dst,
                          int* __restrict__ cursor, int* __restrict__ ssrc) {
  int e = blockIdx.x * blockDim.x + threadIdx.x;
  if (e < NE) {
    int pos = atomicAdd(&cursor[dst[e]], 1);
    ssrc[pos] = src[e];
  }
}

// ---------------- weight convert + input-feature convert (merged) ----------------
// weights: fp32 [k][n] -> bf16 hi/lo planes [n][k]; h: fp32 [N][74] -> bf16*onorm [N][48] uints
__global__ void k_convw(const float* __restrict__ W_in, const float* __restrict__ W_gcr,
                        const float* __restrict__ W1, const float* __restrict__ W2,
                        const float* __restrict__ h, const float* __restrict__ onorm,
                        ushort* __restrict__ Wt0h, ushort* __restrict__ Wt0l,
                        ushort* __restrict__ Wtgh, ushort* __restrict__ Wtgl,
                        ushort* __restrict__ Wt1h, ushort* __restrict__ Wt1l,
                        ushort* __restrict__ Wt2h, ushort* __restrict__ Wt2l,
                        uint* __restrict__ hb) {
  int idx = blockIdx.x * blockDim.x + threadIdx.x;
  const int n0 = 256 * KPAD;
  const int n1 = n0 + 10 * 65536;
  const int n2 = n1 + DM1 * DH;
  const int n3 = n2 + DM2 * DM1;
  const int n4 = n3 + NN * 48;
  if (idx >= n4) return;
  if (idx >= n3) {
    int j = idx - n3;
    int r = j / 48, c = j - r * 48;
    float s = onorm[r];
    int k0 = c * 2;
    float v0 = (k0 < DIN) ? h[(size_t)r * DIN + k0] * s : 0.f;
    float v1 = (k0 + 1 < DIN) ? h[(size_t)r * DIN + k0 + 1] * s : 0.f;
    hb[j] = (uint)f2bf(v0) | ((uint)f2bf(v1) << 16);
    return;
  }
  float v;
  ushort *dh, *dl;
  int o;
  if (idx < n0) {
    int n = idx / KPAD, k = idx - n * KPAD;
    v = (k < DIN) ? W_in[k * DH + n] : 0.f;
    dh = Wt0h; dl = Wt0l; o = idx;
  } else if (idx < n1) {
    int j = idx - n0;
    int l = j >> 16, r = j & 65535;
    int n = r >> 8, k = r & 255;
    v = W_gcr[l * 65536 + k * 256 + n];
    dh = Wtgh; dl = Wtgl; o = l * 65536 + n * 256 + k;
  } else if (idx < n2) {
    int j = idx - n1;
    int n = j >> 8, k = j & 255;
    v = W1[k * DM1 + n];
    dh = Wt1h; dl = Wt1l; o = n * 256 + k;
  } else {
    int j = idx - n2;
    int n = j >> 10, k = j & 1023;
    v = W2[k * DM2 + n];
    dh = Wt2h; dl = Wt2l; o = n * 1024 + k;
  }
  ushort hv = f2bf(v);
  dh[o] = hv;
  dl[o] = f2bf(v - bf2f(hv));
}

// ---------------- input SpMM: 2 rows per wave (24 active lanes/half, uint2), depth-4 ----------------
__global__ void k_spmm74(const uint* __restrict__ hb, const int* __restrict__ offs,
                         const int* __restrict__ ssrc, const float* __restrict__ inorm,
                         ushort* __restrict__ Ahi, ushort* __restrict__ Alo) {
  int wid = blockIdx.x * 4 + (threadIdx.x >> 6);
  int rbase = wid * 2;
  if (rbase >= NN) return;  // NN even: rbase+1 valid whenever rbase is
  int lane = threadIdx.x & 63;
  int l24 = lane & 31;
  int row = rbase + (lane >> 5);
  bool act = l24 < 24;  // 24 lanes x 8B = 192B row
  int beg = offs[row], n = offs[row + 1] - beg;
  int nmax = max(n, __shfl_xor(n, 32));
  const uint* xb = hb + l24 * 2;
  float a0 = 0.f, a1 = 0.f, a2 = 0.f, a3 = 0.f;
  uint2 z = {0, 0};
  uint2 d0 = z, d1 = z, d2 = z, d3 = z;
#define LJ74(dj, e) { dj = z; if (act && (e) < n) \
    dj = *(const uint2*)(xb + (size_t)ssrc[beg + (e)] * 48); }
  LJ74(d0, 0)
  LJ74(d1, 1)
  LJ74(d2, 2)
  LJ74(d3, 3)
  int e = 0;
#define STEP74(dj) { uint2 u = dj; LJ74(dj, e + 4) \
    a0 += __uint_as_float(u.x << 16); a1 += __uint_as_float(u.x & 0xffff0000u); \
    a2 += __uint_as_float(u.y << 16); a3 += __uint_as_float(u.y & 0xffff0000u); ++e; }
  while (e < nmax) {
    STEP74(d0) if (e >= nmax) break;
    STEP74(d1) if (e >= nmax) break;
    STEP74(d2) if (e >= nmax) break;
    STEP74(d3)
  }
#undef STEP74
#undef LJ74
  float win = inorm[row];
  float v0 = a0 * win, v1 = a1 * win, v2 = a2 * win, v3 = a3 * win;
  ushort h0 = f2bf(v0), h1 = f2bf(v1), h2 = f2bf(v2), h3 = f2bf(v3);
  if (act) {
    uint2 oh, ol;
    oh.x = (uint)h0 | ((uint)h1 << 16);
    oh.y = (uint)h2 | ((uint)h3 << 16);
    ol.x = (uint)f2bf(v0 - bf2f(h0)) | ((uint)f2bf(v1 - bf2f(h1)) << 16);
    ol.y = (uint)f2bf(v2 - bf2f(h2)) | ((uint)f2bf(v3 - bf2f(h3)) << 16);
    *(uint2*)&Ahi[(size_t)row * KPAD + l24 * 4] = oh;
    *(uint2*)&Alo[(size_t)row * KPAD + l24 * 4] = ol;
  }
}

// ---------------- conv SpMM: 2 rows per wave (half-wave per row, 16B/lane), depth-4 ----------------
__global__ void k_spmm1(const ushort* __restrict__ xin, const int* __restrict__ offs,
                        const int* __restrict__ ssrc, const float* __restrict__ inorm,
                        ushort* __restrict__ Ah) {
  int wid = blockIdx.x * 4 + (threadIdx.x >> 6);
  int rbase = wid * 2;
  if (rbase >= NN) return;
  int lane = threadIdx.x & 63;
  int l5 = lane & 31;
  int row = rbase + (lane >> 5);
  int beg = offs[row], n = offs[row + 1] - beg;
  int nmax = max(n, __shfl_xor(n, 32));
  const ushort* xb = xin + l5 * 8;  // 16B per lane, 32 lanes cover 512B row
  float a0 = 0.f, a1 = 0.f, a2 = 0.f, a3 = 0.f;
  float a4 = 0.f, a5 = 0.f, a6 = 0.f, a7 = 0.f;
  uint4 z = {0, 0, 0, 0};
  uint4 d0 = z, d1 = z, d2 = z, d3 = z;
#define LJ(dj, e) { dj = z; if ((e) < n) \
    dj = *(const uint4*)(xb + (size_t)ssrc[beg + (e)] * DH); }
  LJ(d0, 0)
  LJ(d1, 1)
  LJ(d2, 2)
  LJ(d3, 3)
  int e = 0;
#define STEP(dj) { uint4 u = dj; LJ(dj, e + 4) \
    a0 += __uint_as_float(u.x << 16); a1 += __uint_as_float(u.x & 0xffff0000u); \
    a2 += __uint_as_float(u.y << 16); a3 += __uint_as_float(u.y & 0xffff0000u); \
    a4 += __uint_as_float(u.z << 16); a5 += __uint_as_float(u.z & 0xffff0000u); \
    a6 += __uint_as_float(u.w << 16); a7 += __uint_as_float(u.w & 0xffff0000u); ++e; }
  while (e < nmax) {
    STEP(d0) if (e >= nmax) break;
    STEP(d1) if (e >= nmax) break;
    STEP(d2) if (e >= nmax) break;
    STEP(d3)
  }
#undef STEP
#undef LJ
  float win = inorm[row];
  uint4 o;
  o.x = (uint)f2bf(a0 * win) | ((uint)f2bf(a1 * win) << 16);
  o.y = (uint)f2bf(a2 * win) | ((uint)f2bf(a3 * win) << 16);
  o.z = (uint)f2bf(a4 * win) | ((uint)f2bf(a5 * win) << 16);
  o.w = (uint)f2bf(a6 * win) | ((uint)f2bf(a7 * win) << 16);
  *(uint4*)(Ah + (size_t)row * DH + l5 * 8) = o;
}

// ---------------- async-staged bf16 MFMA GEMM ----------------
// A: bf16-hi plane [M][K] (+ optional lo plane when ALO=1); B: hi/lo planes [N][K].
// Staging via global_load_lds (16B/lane). XOR chunk swizzle -> free 2-way frag reads.
// ACT: 0=none 1=relu 2=leaky(0.01). OUT: 0=fp32 C0, 1=bf16 hi C0, 2=planes C0/C1
// SCALE: multiply output by oscale[row] (after ACT). ALO: A lo-plane present (3 vs 2 MFMA).
template <int ACT, int OUT, int SCALE, int ALO>
__global__ __launch_bounds__(512, 4) void k_mfma(
    const ushort* __restrict__ Ah, const ushort* __restrict__ Al,
    const ushort* __restrict__ Bh, const ushort* __restrict__ Bl,
    const float* __restrict__ bias, const float* __restrict__ oscale,
    void* __restrict__ C0, void* __restrict__ C1,
    int M, int K, int Nc) {
  __shared__ __align__(16) ushort Ash[128 * 32];
  __shared__ __align__(16) ushort Asl[ALO ? 128 * 32 : 8];
  __shared__ __align__(16) ushort Bsh[256 * 32], Bsl[256 * 32];
  const int tid = threadIdx.x, lane = tid & 63, wv = tid >> 6;
  const int wm = (wv >> 2) * 64, wn = (wv & 3) * 64;
  const int quad = lane >> 4, l15 = lane & 15;
  const int r0 = blockIdx.x * 128, c0 = blockIdx.y * 256;

  const int srow = lane >> 2, clds = lane & 3;
  const int arow = 16 * wv + srow;
  const int acg = clds ^ ((arow >> 1) & 3);
  int agr = r0 + arow;
  if (agr > M - 1) agr = M - 1;  // clamp; epilogue masks stores
  const size_t aoff = (size_t)agr * K + acg * 8;
  const int brow0 = 16 * wv + srow, brow1 = brow0 + 128;
  const int bcg0 = clds ^ ((brow0 >> 1) & 3);
  const int bcg1 = clds ^ ((brow1 >> 1) & 3);
  const size_t boff0 = (size_t)(c0 + brow0) * K + bcg0 * 8;
  const size_t boff1 = (size_t)(c0 + brow1) * K + bcg1 * 8;
  ushort* lAh = &Ash[(16 * wv) * 32];
  ushort* lAl = &Asl[ALO ? (16 * wv) * 32 : 0];
  ushort* lB0h = &Bsh[(16 * wv) * 32];
  ushort* lB0l = &Bsl[(16 * wv) * 32];
  ushort* lB1h = &Bsh[(16 * wv + 128) * 32];
  ushort* lB1l = &Bsl[(16 * wv + 128) * 32];

  f32x4 acc[4][4] = {};
  const int nk = K >> 5;
  for (int s = 0; s < nk; ++s) {
    const int k0 = s << 5;
    __syncthreads();
    gll16(Ah + aoff + k0, lAh);
    if (ALO) gll16(Al + aoff + k0, lAl);
    gll16(Bh + boff0 + k0, lB0h);
    gll16(Bl + boff0 + k0, lB0l);
    gll16(Bh + boff1 + k0, lB1h);
    gll16(Bl + boff1 + k0, lB1l);
    __syncthreads();
    short8 ah[4], al[4];
#pragma unroll
    for (int t = 0; t < 4; ++t) {
      int r = wm + t * 16 + l15;
      int sa = (quad ^ ((r >> 1) & 3)) << 3;
      ah[t] = *(const short8*)&Ash[r * 32 + sa];
      if (ALO) al[t] = *(const short8*)&Asl[r * 32 + sa];
    }
#pragma unroll
    for (int nt = 0; nt < 4; ++nt) {
      int rb = wn + nt * 16 + l15;
      int sb = (quad ^ ((rb >> 1) & 3)) << 3;
      short8 bh = *(const short8*)&Bsh[rb * 32 + sb];
      short8 bl = *(const short8*)&Bsl[rb * 32 + sb];
#pragma unroll
      for (int mt = 0; mt < 4; ++mt) {
        acc[mt][nt] = __builtin_amdgcn_mfma_f32_16x16x32_bf16(ah[mt], bh, acc[mt][nt], 0, 0, 0);
        acc[mt][nt] = __builtin_amdgcn_mfma_f32_16x16x32_bf16(ah[mt], bl, acc[mt][nt], 0, 0, 0);
        if (ALO)
          acc[mt][nt] = __builtin_amdgcn_mfma_f32_16x16x32_bf16(al[mt], bh, acc[mt][nt], 0, 0, 0);
      }
    }
  }

  float bv[4];
#pragma unroll
  for (int nt = 0; nt < 4; ++nt) bv[nt] = bias[c0 + wn + nt * 16 + l15];
#pragma unroll
  for (int mt = 0; mt < 4; ++mt) {
#pragma unroll
    for (int r = 0; r < 4; ++r) {
      int gr = r0 + wm + mt * 16 + quad * 4 + r;
      if (gr >= M) continue;
      float osc = SCALE ? oscale[gr] : 1.f;
#pragma unroll
      for (int nt = 0; nt < 4; ++nt) {
        int gc = c0 + wn + nt * 16 + l15;
        float v = acc[mt][nt][r] + bv[nt];
        if (ACT == 1) v = fmaxf(v, 0.f);
        if (ACT == 2) v = (v > 0.f) ? v : 0.01f * v;
        if (SCALE) v *= osc;
        size_t idx = (size_t)gr * Nc + gc;
        if (OUT == 0) {
          ((float*)C0)[idx] = v;
        } else if (OUT == 1) {
          ((ushort*)C0)[idx] = f2bf(v);
        } else {
          ushort hv = f2bf(v);
          ((ushort*)C0)[idx] = hv;
          ((ushort*)C1)[idx] = f2bf(v - bf2f(hv));
        }
      }
    }
  }
}

// ---------------- pooling + tail ----------------
__global__ void k_gbounds(const int* __restrict__ gid, int* __restrict__ gstart) {
  int g = blockIdx.x * blockDim.x + threadIdx.x;
  if (g > NG) return;
  int lo = 0, hi = NN;
  while (lo < hi) {
    int mid = (lo + hi) >> 1;
    if (gid[mid] < g) lo = mid + 1; else hi = mid;
  }
  gstart[g] = lo;
}

__global__ void k_pool(const ushort* __restrict__ xh, const int* __restrict__ gstart,
                       ushort* __restrict__ ph, ushort* __restrict__ pl) {
  int g = blockIdx.x * 4 + (threadIdx.x >> 6);
  if (g >= NG) return;
  int lane = threadIdx.x & 63;
  int beg = gstart[g], end = gstart[g + 1];
  float a0 = 0.f, a1 = 0.f, a2 = 0.f, a3 = 0.f;
  for (int r = beg; r < end; ++r) {
    uint2 u = *(const uint2*)(xh + (size_t)r * DH + lane * 4);
    a0 += __uint_as_float(u.x << 16);
    a1 += __uint_as_float(u.x & 0xffff0000u);
    a2 += __uint_as_float(u.y << 16);
    a3 += __uint_as_float(u.y & 0xffff0000u);
  }
  float inv = 1.f / fmaxf((float)(end - beg), 1.f);
  float o[4] = {a0 * inv, a1 * inv, a2 * inv, a3 * inv};
  ushort4 hv, lv;
  hv.x = f2bf(o[0]); lv.x = f2bf(o[0] - bf2f(hv.x));
  hv.y = f2bf(o[1]); lv.y = f2bf(o[1] - bf2f(hv.y));
  hv.z = f2bf(o[2]); lv.z = f2bf(o[2] - bf2f(hv.z));
  hv.w = f2bf(o[3]); lv.w = f2bf(o[3] - bf2f(hv.w));
  *(ushort4*)(ph + (size_t)g * DH + lane * 4) = hv;
  *(ushort4*)(pl + (size_t)g * DH + lane * 4) = lv;
}

__global__ void k_out(const float* __restrict__ z2, const float* __restrict__ W3,
                      const float* __restrict__ b3, float* __restrict__ out) {
  int g = blockIdx.x * 4 + (threadIdx.x >> 6);
  if (g >= NG) return;
  int lane = threadIdx.x & 63;
  float s = 0.f;
  const float* zr = z2 + (size_t)g * DM2;
  for (int k = lane; k < DM2; k += 64) s += zr[k] * W3[k];
  for (int off = 32; off > 0; off >>= 1) s += __shfl_down(s, off);
  if (lane == 0) out[g] = s + b3[0];
}

// ---------------- launcher ----------------
extern "C" void kernel_launch(void* const* d_in, const int* in_sizes, int n_in,
                              void* d_out, int out_size, void* d_ws, size_t ws_size,
                              hipStream_t stream) {
  (void)in_sizes; (void)n_in; (void)out_size; (void)ws_size;
  const float* h     = (const float*)d_in[0];
  const int*   src   = (const int*)d_in[1];
  const int*   dst   = (const int*)d_in[2];
  const int*   gid   = (const int*)d_in[3];
  const float* W_in  = (const float*)d_in[4];
  const float* b_in  = (const float*)d_in[5];
  const float* W_gcr = (const float*)d_in[6];
  const float* b_gcr = (const float*)d_in[7];
  const float* W1    = (const float*)d_in[8];
  const float* b1    = (const float*)d_in[9];
  const float* W2    = (const float*)d_in[10];
  const float* b2    = (const float*)d_in[11];
  const float* W3    = (const float*)d_in[12];
  const float* b3    = (const float*)d_in[13];
  float* out = (float*)d_out;

  char* p = (char*)d_ws;
  auto alloc = [&](size_t bytes) {
    char* q = p;
    p += (bytes + 255) & ~(size_t)255;
    return q;
  };
  int*    outdeg = (int*)alloc((size_t)NN * 4);
  int*    indeg  = (int*)alloc((size_t)NN * 4);
  float*  onorm  = (float*)alloc((size_t)NN * 4);
  float*  inorm  = (float*)alloc((size_t)NN * 4);
  int*    incl   = (int*)alloc((size_t)NN * 4);
  int*    bsum   = (int*)alloc(128 * 4);
  int*    offs   = (int*)alloc((size_t)(NN + 1) * 4);
  int*    cursor = (int*)alloc((size_t)NN * 4);
  int*    ssrc   = (int*)alloc((size_t)NE * 4);
  int*    gstart = (int*)alloc((size_t)(NG + 1) * 4);
  uint*   hb     = (uint*)alloc((size_t)NN * 48 * 4);
  ushort* xh0    = (ushort*)alloc((size_t)NN * DH * 2);
  ushort* xh1    = (ushort*)alloc((size_t)NN * DH * 2);
  ushort* Ah1    = (ushort*)alloc((size_t)NN * DH * 2);
  ushort* A0h    = (ushort*)alloc((size_t)NN * KPAD * 2);
  ushort* A0l    = (ushort*)alloc((size_t)NN * KPAD * 2);
  ushort* Wt0h   = (ushort*)alloc((size_t)256 * KPAD * 2);
  ushort* Wt0l   = (ushort*)alloc((size_t)256 * KPAD * 2);
  ushort* Wtgh   = (ushort*)alloc((size_t)10 * 65536 * 2);
  ushort* Wtgl   = (ushort*)alloc((size_t)10 * 65536 * 2);
  ushort* Wt1h   = (ushort*)alloc((size_t)DM1 * DH * 2);
  ushort* Wt1l   = (ushort*)alloc((size_t)DM1 * DH * 2);
  ushort* Wt2h   = (ushort*)alloc((size_t)DM2 * DM1 * 2);
  ushort* Wt2l   = (ushort*)alloc((size_t)DM2 * DM1 * 2);
  ushort* plh    = (ushort*)alloc((size_t)NG * DH * 2);
  ushort* pll    = (ushort*)alloc((size_t)NG * DH * 2);
  ushort* z1h    = (ushort*)alloc((size_t)NG * DM1 * 2);
  ushort* z1l    = (ushort*)alloc((size_t)NG * DM1 * 2);
  float*  z2     = (float*)alloc((size_t)NG * DM2 * 4);

  hipMemsetAsync(outdeg, 0, (size_t)NN * 4, stream);
  hipMemsetAsync(indeg, 0, (size_t)NN * 4, stream);
  k_deg<<<(NE + 255) / 256, 256, 0, stream>>>(src, dst, outdeg, indeg);
  int nb = (NN + 1023) / 1024;
  k_scan_block<<<nb, 1024, 0, stream>>>(indeg, incl, bsum, NN);
  k_scan_sums<<<1, 64, 0, stream>>>(bsum, nb);
  k_scan_add<<<(NN + 255) / 256, 256, 0, stream>>>(incl, bsum, indeg, outdeg,
                                                   offs, cursor, onorm, inorm, NN);
  k_scatter<<<(NE + 255) / 256, 256, 0, stream>>>(src, dst, cursor, ssrc);

  const int nconv = 256 * KPAD + 10 * 65536 + DM1 * DH + DM2 * DM1 + NN * 48;
  k_convw<<<(nconv + 255) / 256, 256, 0, stream>>>(W_in, W_gcr, W1, W2, h, onorm,
                                                   Wt0h, Wt0l, Wtgh, Wtgl,
                                                   Wt1h, Wt1l, Wt2h, Wt2l, hb);

  // input conv: gather pre-scaled bf16 h (pad 96), hi/lo GEMM 96->256, no act,
  // output bf16-hi pre-scaled by onorm (ready for next gather)
  k_spmm74<<<(NN + 7) / 8, 256, 0, stream>>>(hb, offs, ssrc, inorm, A0h, A0l);
  dim3 gmm((NN + 127) / 128, 1);
  k_mfma<0, 1, 1, 1><<<gmm, 512, 0, stream>>>(A0h, A0l, Wt0h, Wt0l, b_in, onorm,
                                              xh0, nullptr, NN, KPAD, DH);

  // 10 conv layers: 2-row/wave gather -> A-hi plane -> 2-term MFMA GEMM + relu.
  // Layers 0..8 output pre-scaled by onorm; layer 9 unscaled for pooling.
  ushort* xin = xh0;
  ushort* xout = xh1;
  for (int li = 0; li < 10; ++li) {
    k_spmm1<<<(NN + 7) / 8, 256, 0, stream>>>(xin, offs, ssrc, inorm, Ah1);
    const ushort* bh = Wtgh + (size_t)li * 65536;
    const ushort* bl = Wtgl + (size_t)li * 65536;
    const float* bb = b_gcr + li * 256;
    if (li < 9)
      k_mfma<1, 1, 1, 0><<<gmm, 512, 0, stream>>>(Ah1, nullptr, bh, bl, bb, onorm,
                                                  xout, nullptr, NN, DH, DH);
    else
      k_mfma<1, 1, 0, 0><<<gmm, 512, 0, stream>>>(Ah1, nullptr, bh, bl, bb, nullptr,
                                                  xout, nullptr, NN, DH, DH);
    ushort* t = xin; xin = xout; xout = t;
  }

  k_gbounds<<<(NG + 1 + 255) / 256, 256, 0, stream>>>(gid, gstart);
  k_pool<<<(NG + 3) / 4, 256, 0, stream>>>(xin, gstart, plh, pll);

  dim3 gt1(NG / 128, DM1 / 256);
  k_mfma<2, 2, 0, 1><<<gt1, 512, 0, stream>>>(plh, pll, Wt1h, Wt1l, b1, nullptr,
                                              z1h, z1l, NG, DH, DM1);
  dim3 gt2(NG / 128, DM2 / 256);
  k_mfma<2, 0, 0, 1><<<gt2, 512, 0, stream>>>(z1h, z1l, Wt2h, Wt2l, b2, nullptr,
                                              z2, nullptr, NG, DM1, DM2);
  k_out<<<(NG + 3) / 4, 256, 0, stream>>>(z2, W3, b3, out);
}